// Round 3
// baseline (348.886 us; speedup 1.0000x reference)
//
#include <hip/hip_runtime.h>
#include <hip/hip_bf16.h>
#include <stdint.h>

typedef unsigned short u16;
typedef __attribute__((ext_vector_type(8))) short short8;
typedef __attribute__((ext_vector_type(4))) float f32x4;

#define T_SEQ 2048
#define EMB   1024
#define NH    16
#define HD    64

__device__ __forceinline__ u16 f2bf(float f) {
    union { float f; uint32_t u; } x; x.f = f;
    uint32_t u = x.u;
    uint32_t r = u + 0x7fffu + ((u >> 16) & 1u);   // RNE
    return (u16)(r >> 16);
}

// async global -> LDS, 16 bytes per lane (wave-uniform LDS base + lane*16)
__device__ __forceinline__ void gld16(const void* g, void* l) {
    __builtin_amdgcn_global_load_lds(
        (const __attribute__((address_space(1))) void*)g,
        (__attribute__((address_space(3))) void*)l, 16, 0, 0);
}

// ---------------- cast fp32 -> bf16 (vectorized) ----------------
__global__ __launch_bounds__(256) void cast_bf16_kernel(const float* __restrict__ in,
                                                        u16* __restrict__ out, int n4) {
    int i = blockIdx.x * 256 + threadIdx.x;
    if (i < n4) {
        float4 v = ((const float4*)in)[i];
        uint32_t p0 = (uint32_t)f2bf(v.x) | ((uint32_t)f2bf(v.y) << 16);
        uint32_t p1 = (uint32_t)f2bf(v.z) | ((uint32_t)f2bf(v.w) << 16);
        ((uint2*)out)[i] = make_uint2(p0, p1);
    }
}

// ---------------- transpose + cast: Wt[n][k] = bf16(W[k][n]) ----------------
__global__ __launch_bounds__(256) void transpose_cast_kernel(const float* __restrict__ W,
                                                             u16* __restrict__ Wt,
                                                             int K, int N) {
    __shared__ float tile[32][33];
    int n0 = blockIdx.x * 32, k0 = blockIdx.y * 32;
    int tx = threadIdx.x, ty = threadIdx.y;   // 32 x 8
#pragma unroll
    for (int i = 0; i < 4; i++)
        tile[ty + i * 8][tx] = W[(k0 + ty + i * 8) * N + n0 + tx];
    __syncthreads();
#pragma unroll
    for (int i = 0; i < 4; i++)
        Wt[(size_t)(n0 + ty + i * 8) * K + k0 + tx] = f2bf(tile[tx][ty + i * 8]);
}

// ---------------- 128x128 tile GEMM core (K=1024, BK=32, 4 waves) ----------------
__device__ __forceinline__ void gemm_tile(const u16* __restrict__ A, const u16* __restrict__ Bt,
                                          int m0, int n0, f32x4 (&acc)[4][4],
                                          u16* As, u16* Bs, int tid) {
    const int lane = tid & 63;
    const int wid  = tid >> 6;
    const int wr = wid >> 1, wc = wid & 1;
    const int g = lane >> 4, r = lane & 15;
#pragma unroll
    for (int m = 0; m < 4; m++)
#pragma unroll
        for (int n = 0; n < 4; n++) acc[m][n] = (f32x4){0.f, 0.f, 0.f, 0.f};

    for (int kk = 0; kk < 1024; kk += 32) {
        __syncthreads();
#pragma unroll
        for (int c = 0; c < 2; c++) {
            int ofs = tid * 16 + c * 4096;       // byte offset into 8KB tile
            int row = ofs >> 6;                  // row stride = 32 bf16 = 64B
            int kb  = (ofs & 63) >> 1;
            gld16(&A[(size_t)(m0 + row) * 1024 + kk + kb], &As[ofs >> 1]);
            gld16(&Bt[(size_t)(n0 + row) * 1024 + kk + kb], &Bs[ofs >> 1]);
        }
        __syncthreads();
        short8 af[4], bf[4];
#pragma unroll
        for (int m = 0; m < 4; m++) af[m] = *(short8*)&As[(wr * 64 + m * 16 + r) * 32 + g * 8];
#pragma unroll
        for (int n = 0; n < 4; n++) bf[n] = *(short8*)&Bs[(wc * 64 + n * 16 + r) * 32 + g * 8];
#pragma unroll
        for (int m = 0; m < 4; m++)
#pragma unroll
            for (int n = 0; n < 4; n++)
                acc[m][n] = __builtin_amdgcn_mfma_f32_16x16x32_bf16(af[m], bf[n], acc[m][n], 0, 0, 0);
    }
}

// ---------------- QKV GEMM: Q (pre-scaled by 1/8), K -> [B,H,T,D]; V -> VT [B,H,D,T] ----------------
__global__ __launch_bounds__(256) void gemm_qkv_kernel(const u16* __restrict__ A, const u16* __restrict__ Bt,
                                                       const float* __restrict__ bias,
                                                       u16* __restrict__ Qo, u16* __restrict__ Ko,
                                                       u16* __restrict__ VTo) {
    __shared__ __align__(16) u16 As[128 * 32];
    __shared__ __align__(16) u16 Bs[128 * 32];
    int tid = threadIdx.x;
    int m0 = blockIdx.x * 128, n0 = blockIdx.y * 128;
    f32x4 acc[4][4];
    gemm_tile(A, Bt, m0, n0, acc, As, Bs, tid);

    int lane = tid & 63, wid = tid >> 6;
    int wr = wid >> 1, wc = wid & 1, g = lane >> 4, r = lane & 15;
#pragma unroll
    for (int m = 0; m < 4; m++) {
#pragma unroll
        for (int n = 0; n < 4; n++) {
            int col = n0 + wc * 64 + n * 16 + r;     // [0,3072)
            float bv = bias[col];
            int which = col >> 10;
            int e = col & 1023;
            int h = e >> 6, d = e & 63;
            int row0 = m0 + wr * 64 + m * 16 + g * 4;   // token base, multiple of 4
            int b = row0 >> 11, t0 = row0 & 2047;
            if (which == 2) {
                ushort4 pk;
                pk.x = f2bf(acc[m][n][0] + bv);
                pk.y = f2bf(acc[m][n][1] + bv);
                pk.z = f2bf(acc[m][n][2] + bv);
                pk.w = f2bf(acc[m][n][3] + bv);
                *(ushort4*)&VTo[(((size_t)(b * NH + h)) * HD + d) * T_SEQ + t0] = pk;
            } else {
                u16* dst = which ? Ko : Qo;
                float sc = which ? 1.0f : 0.125f;     // fold 1/sqrt(D) into Q
#pragma unroll
                for (int j = 0; j < 4; j++)
                    dst[(((size_t)(b * NH + h)) * T_SEQ + t0 + j) * HD + d] = f2bf((acc[m][n][j] + bv) * sc);
            }
        }
    }
}

// ---------------- output GEMM: fp32 out = A @ Wout + b ----------------
__global__ __launch_bounds__(256) void gemm_out_kernel(const u16* __restrict__ A, const u16* __restrict__ Bt,
                                                       const float* __restrict__ bias,
                                                       float* __restrict__ out) {
    __shared__ __align__(16) u16 As[128 * 32];
    __shared__ __align__(16) u16 Bs[128 * 32];
    int tid = threadIdx.x;
    int m0 = blockIdx.x * 128, n0 = blockIdx.y * 128;
    f32x4 acc[4][4];
    gemm_tile(A, Bt, m0, n0, acc, As, Bs, tid);

    int lane = tid & 63, wid = tid >> 6;
    int wr = wid >> 1, wc = wid & 1, g = lane >> 4, r = lane & 15;
#pragma unroll
    for (int m = 0; m < 4; m++) {
#pragma unroll
        for (int n = 0; n < 4; n++) {
            int col = n0 + wc * 64 + n * 16 + r;
            float bv = bias[col];
#pragma unroll
            for (int j = 0; j < 4; j++) {
                int row = m0 + wr * 64 + m * 16 + g * 4 + j;
                out[(size_t)row * 1024 + col] = acc[m][n][j] + bv;
            }
        }
    }
}

// ---------------- causal flash attention, swapped-QK^T, scalar-per-lane softmax ----
// grid: (32, B*H). block: 256 (4 waves x 16 q-rows). qt = 31 - blockIdx.x so the
// longest blocks launch first. Q,K: [B*H][T][64]; VT: [B*H][64][T].
// S^T = mfma(K, Q): lane (r,g) holds q = q0+wid*16+r (fixed), k = k0+nt*16+4g+j.
__global__ __launch_bounds__(256) void attn_kernel(const u16* __restrict__ Q, const u16* __restrict__ K,
                                                   const u16* __restrict__ VT, u16* __restrict__ O) {
    __shared__ __align__(16) u16 Ps[4][16][72];     // per-wave P (q-major), padded

    const int tid = threadIdx.x;
    const int lane = tid & 63, wid = tid >> 6;
    const int g = lane >> 4, r = lane & 15;
    const int bh = blockIdx.y;
    const int b = bh >> 4, h = bh & 15;
    const u16* Qb  = Q  + (size_t)bh * T_SEQ * HD;
    const u16* Kb  = K  + (size_t)bh * T_SEQ * HD;
    const u16* VTb = VT + (size_t)bh * HD * T_SEQ;
    u16 (*myPs)[72] = Ps[wid];

    const int qt = 31 - (int)blockIdx.x;
    const int q0 = qt * 64;
    const int q  = q0 + wid * 16 + r;            // this lane's q row (fixed)

    // Q fragments (B-operand: col = lane%16 -> q, 8 contiguous d per lane)
    short8 qf0 = *(const short8*)&Qb[(size_t)q * HD + 8 * g];
    short8 qf1 = *(const short8*)&Qb[(size_t)q * HD + 32 + 8 * g];

    float mrun = -1e30f, srun = 0.f;
    f32x4 o[4];
#pragma unroll
    for (int dt = 0; dt < 4; dt++) o[dt] = (f32x4){0.f, 0.f, 0.f, 0.f};

    // preload K tile 0 (A-operand: row = lane%16 -> k, 8 contiguous d per lane)
    short8 kc0[4], kc1[4];
#pragma unroll
    for (int nt = 0; nt < 4; nt++) {
        kc0[nt] = *(const short8*)&Kb[(size_t)(nt * 16 + r) * HD + 8 * g];
        kc1[nt] = *(const short8*)&Kb[(size_t)(nt * 16 + r) * HD + 32 + 8 * g];
    }

    for (int kv = 0; kv <= qt; kv++) {
        const int k0 = kv * 64;

        // V^T fragments (A-operand for PV: row = d, contraction k)
        short8 vf0[4], vf1[4];
#pragma unroll
        for (int dt = 0; dt < 4; dt++) {
            vf0[dt] = *(const short8*)&VTb[(size_t)(dt * 16 + r) * T_SEQ + k0 + 8 * g];
            vf1[dt] = *(const short8*)&VTb[(size_t)(dt * 16 + r) * T_SEQ + k0 + 32 + 8 * g];
        }

        // S^T = K Q^T (Q pre-scaled by 1/8): s[nt][j] -> k = k0+nt*16+4g+j, this lane's q
        f32x4 s[4];
        __builtin_amdgcn_s_setprio(1);
#pragma unroll
        for (int nt = 0; nt < 4; nt++) {
            f32x4 z = (f32x4){0.f, 0.f, 0.f, 0.f};
            z = __builtin_amdgcn_mfma_f32_16x16x32_bf16(kc0[nt], qf0, z, 0, 0, 0);
            z = __builtin_amdgcn_mfma_f32_16x16x32_bf16(kc1[nt], qf1, z, 0, 0, 0);
            s[nt] = z;
        }
        __builtin_amdgcn_s_setprio(0);

        // prefetch next K tile (hidden under softmax + PV)
        if (kv < qt) {
            const int k1 = k0 + 64;
#pragma unroll
            for (int nt = 0; nt < 4; nt++) {
                kc0[nt] = *(const short8*)&Kb[(size_t)(k1 + nt * 16 + r) * HD + 8 * g];
                kc1[nt] = *(const short8*)&Kb[(size_t)(k1 + nt * 16 + r) * HD + 32 + 8 * g];
            }
        }

        // causal mask (diagonal tile only)
        if (kv == qt) {
#pragma unroll
            for (int nt = 0; nt < 4; nt++) {
                int kb = k0 + nt * 16 + 4 * g;
#pragma unroll
                for (int j = 0; j < 4; j++)
                    if (kb + j > q) s[nt][j] = -1e30f;
            }
        }

        // row max: 15 in-lane + 2 shuffle rounds (lanes r, r+16, r+32, r+48)
        float mt = s[0][0];
#pragma unroll
        for (int nt = 0; nt < 4; nt++)
#pragma unroll
            for (int j = 0; j < 4; j++) mt = fmaxf(mt, s[nt][j]);
        mt = fmaxf(mt, __shfl_xor(mt, 16));
        mt = fmaxf(mt, __shfl_xor(mt, 32));

        // online softmax (scalar state per lane)
        float mn = fmaxf(mrun, mt);
        float corr = __expf(mrun - mn);
        mrun = mn;
        float psum = 0.f;
#pragma unroll
        for (int nt = 0; nt < 4; nt++)
#pragma unroll
            for (int j = 0; j < 4; j++) {
                float p = __expf(s[nt][j] - mn);
                s[nt][j] = p;
                psum += p;
            }
        psum += __shfl_xor(psum, 16);
        psum += __shfl_xor(psum, 32);
        srun = srun * corr + psum;
#pragma unroll
        for (int dt = 0; dt < 4; dt++)
#pragma unroll
            for (int j = 0; j < 4; j++) o[dt][j] *= corr;

        // P -> LDS, packed: lane (r,g) owns k = nt*16+4g..+3 of q-row r (4x ds_write_b64)
#pragma unroll
        for (int nt = 0; nt < 4; nt++) {
            ushort4 pk;
            pk.x = f2bf(s[nt][0]);
            pk.y = f2bf(s[nt][1]);
            pk.z = f2bf(s[nt][2]);
            pk.w = f2bf(s[nt][3]);
            *(ushort4*)&myPs[r][nt * 16 + 4 * g] = pk;
        }
        // B-operand fragments of P (col = q, contraction k)
        short8 pf0 = *(short8*)&myPs[r][8 * g];
        short8 pf1 = *(short8*)&myPs[r][32 + 8 * g];

        __builtin_amdgcn_s_setprio(1);
#pragma unroll
        for (int dt = 0; dt < 4; dt++) {
            o[dt] = __builtin_amdgcn_mfma_f32_16x16x32_bf16(vf0[dt], pf0, o[dt], 0, 0, 0);
            o[dt] = __builtin_amdgcn_mfma_f32_16x16x32_bf16(vf1[dt], pf1, o[dt], 0, 0, 0);
        }
        __builtin_amdgcn_s_setprio(0);
    }

    // epilogue: O^T regs -> O[b][t][h][d], 4 consecutive d per 8B store
    float inv = 1.f / srun;
#pragma unroll
    for (int dt = 0; dt < 4; dt++) {
        ushort4 pk;
        pk.x = f2bf(o[dt][0] * inv);
        pk.y = f2bf(o[dt][1] * inv);
        pk.z = f2bf(o[dt][2] * inv);
        pk.w = f2bf(o[dt][3] * inv);
        *(ushort4*)&O[(((size_t)(b * T_SEQ + q)) * NH + h) * HD + dt * 16 + 4 * g] = pk;
    }
}

extern "C" void kernel_launch(void* const* d_in, const int* in_sizes, int n_in,
                              void* d_out, int out_size, void* d_ws, size_t ws_size,
                              hipStream_t stream) {
    const float* x     = (const float*)d_in[0];
    const float* W_qkv = (const float*)d_in[1];
    const float* b_qkv = (const float*)d_in[2];
    const float* W_out = (const float*)d_in[3];
    const float* b_out = (const float*)d_in[4];
    float* out = (float*)d_out;

    char* ws = (char*)d_ws;
    u16* xb    = (u16*)(ws);
    u16* wqkvt = (u16*)(ws + 8388608);
    u16* woutt = (u16*)(ws + 14680064);
    u16* Qp    = (u16*)(ws + 16777216);
    u16* Kp    = (u16*)(ws + 25165824);
    u16* VTp   = (u16*)(ws + 33554432);
    u16* attnb = (u16*)(ws);   // alias xb (dead after gemm_qkv)

    cast_bf16_kernel<<<4096, 256, 0, stream>>>(x, xb, 1048576);
    transpose_cast_kernel<<<dim3(96, 32), dim3(32, 8), 0, stream>>>(W_qkv, wqkvt, 1024, 3072);
    transpose_cast_kernel<<<dim3(32, 32), dim3(32, 8), 0, stream>>>(W_out, woutt, 1024, 1024);
    gemm_qkv_kernel<<<dim3(32, 24), 256, 0, stream>>>(xb, wqkvt, b_qkv, Qp, Kp, VTp);
    attn_kernel<<<dim3(32, 32), 256, 0, stream>>>(Qp, Kp, VTp, attnb);
    gemm_out_kernel<<<dim3(32, 8), 256, 0, stream>>>(attnb, woutt, b_out, out);
}

// Round 4
// 212.140 us; speedup vs baseline: 1.6446x; 1.6446x over previous
//
#include <hip/hip_runtime.h>
#include <hip/hip_bf16.h>
#include <stdint.h>

typedef unsigned short u16;
typedef __attribute__((ext_vector_type(8))) short short8;
typedef __attribute__((ext_vector_type(4))) float f32x4;

#define T_SEQ 2048
#define EMB   1024
#define NH    16
#define HD    64

__device__ __forceinline__ u16 f2bf(float f) {
    union { float f; uint32_t u; } x; x.f = f;
    uint32_t u = x.u;
    uint32_t r = u + 0x7fffu + ((u >> 16) & 1u);   // RNE
    return (u16)(r >> 16);
}

// async global -> LDS, 16 bytes per lane (wave-uniform LDS base + lane*16)
__device__ __forceinline__ void gld16(const void* g, void* l) {
    __builtin_amdgcn_global_load_lds(
        (const __attribute__((address_space(1))) void*)g,
        (__attribute__((address_space(3))) void*)l, 16, 0, 0);
}

// ---------------- cast fp32 -> bf16 (vectorized) ----------------
__global__ __launch_bounds__(256) void cast_bf16_kernel(const float* __restrict__ in,
                                                        u16* __restrict__ out, int n4) {
    int i = blockIdx.x * 256 + threadIdx.x;
    if (i < n4) {
        float4 v = ((const float4*)in)[i];
        uint32_t p0 = (uint32_t)f2bf(v.x) | ((uint32_t)f2bf(v.y) << 16);
        uint32_t p1 = (uint32_t)f2bf(v.z) | ((uint32_t)f2bf(v.w) << 16);
        ((uint2*)out)[i] = make_uint2(p0, p1);
    }
}

// ---------------- transpose + cast: Wt[n][k] = bf16(W[k][n]) ----------------
__global__ __launch_bounds__(256) void transpose_cast_kernel(const float* __restrict__ W,
                                                             u16* __restrict__ Wt,
                                                             int K, int N) {
    __shared__ float tile[32][33];
    int n0 = blockIdx.x * 32, k0 = blockIdx.y * 32;
    int tx = threadIdx.x, ty = threadIdx.y;   // 32 x 8
#pragma unroll
    for (int i = 0; i < 4; i++)
        tile[ty + i * 8][tx] = W[(k0 + ty + i * 8) * N + n0 + tx];
    __syncthreads();
#pragma unroll
    for (int i = 0; i < 4; i++)
        Wt[(size_t)(n0 + ty + i * 8) * K + k0 + tx] = f2bf(tile[tx][ty + i * 8]);
}

// ---------------- 128x128 tile GEMM core (K=1024, BK=32, 4 waves) ----------------
__device__ __forceinline__ void gemm_tile(const u16* __restrict__ A, const u16* __restrict__ Bt,
                                          int m0, int n0, f32x4 (&acc)[4][4],
                                          u16* As, u16* Bs, int tid) {
    const int lane = tid & 63;
    const int wid  = tid >> 6;
    const int wr = wid >> 1, wc = wid & 1;
    const int g = lane >> 4, r = lane & 15;
#pragma unroll
    for (int m = 0; m < 4; m++)
#pragma unroll
        for (int n = 0; n < 4; n++) acc[m][n] = (f32x4){0.f, 0.f, 0.f, 0.f};

    for (int kk = 0; kk < 1024; kk += 32) {
        __syncthreads();
#pragma unroll
        for (int c = 0; c < 2; c++) {
            int ofs = tid * 16 + c * 4096;       // byte offset into 8KB tile
            int row = ofs >> 6;                  // row stride = 32 bf16 = 64B
            int kb  = (ofs & 63) >> 1;
            gld16(&A[(size_t)(m0 + row) * 1024 + kk + kb], &As[ofs >> 1]);
            gld16(&Bt[(size_t)(n0 + row) * 1024 + kk + kb], &Bs[ofs >> 1]);
        }
        __syncthreads();
        short8 af[4], bf[4];
#pragma unroll
        for (int m = 0; m < 4; m++) af[m] = *(short8*)&As[(wr * 64 + m * 16 + r) * 32 + g * 8];
#pragma unroll
        for (int n = 0; n < 4; n++) bf[n] = *(short8*)&Bs[(wc * 64 + n * 16 + r) * 32 + g * 8];
#pragma unroll
        for (int m = 0; m < 4; m++)
#pragma unroll
            for (int n = 0; n < 4; n++)
                acc[m][n] = __builtin_amdgcn_mfma_f32_16x16x32_bf16(af[m], bf[n], acc[m][n], 0, 0, 0);
    }
}

// ---------------- QKV GEMM: Q (pre-scaled by 1/8), K -> [B,H,T,D]; V -> VT [B,H,D,T] ----------------
__global__ __launch_bounds__(256) void gemm_qkv_kernel(const u16* __restrict__ A, const u16* __restrict__ Bt,
                                                       const float* __restrict__ bias,
                                                       u16* __restrict__ Qo, u16* __restrict__ Ko,
                                                       u16* __restrict__ VTo) {
    __shared__ __align__(16) u16 As[128 * 32];
    __shared__ __align__(16) u16 Bs[128 * 32];
    int tid = threadIdx.x;
    int m0 = blockIdx.x * 128, n0 = blockIdx.y * 128;
    f32x4 acc[4][4];
    gemm_tile(A, Bt, m0, n0, acc, As, Bs, tid);

    int lane = tid & 63, wid = tid >> 6;
    int wr = wid >> 1, wc = wid & 1, g = lane >> 4, r = lane & 15;
#pragma unroll
    for (int m = 0; m < 4; m++) {
#pragma unroll
        for (int n = 0; n < 4; n++) {
            int col = n0 + wc * 64 + n * 16 + r;     // [0,3072)
            float bv = bias[col];
            int which = col >> 10;
            int e = col & 1023;
            int h = e >> 6, d = e & 63;
            int row0 = m0 + wr * 64 + m * 16 + g * 4;   // token base, multiple of 4
            int b = row0 >> 11, t0 = row0 & 2047;
            if (which == 2) {
                ushort4 pk;
                pk.x = f2bf(acc[m][n][0] + bv);
                pk.y = f2bf(acc[m][n][1] + bv);
                pk.z = f2bf(acc[m][n][2] + bv);
                pk.w = f2bf(acc[m][n][3] + bv);
                *(ushort4*)&VTo[(((size_t)(b * NH + h)) * HD + d) * T_SEQ + t0] = pk;
            } else {
                u16* dst = which ? Ko : Qo;
                float sc = which ? 1.0f : 0.125f;     // fold 1/sqrt(D) into Q
#pragma unroll
                for (int j = 0; j < 4; j++)
                    dst[(((size_t)(b * NH + h)) * T_SEQ + t0 + j) * HD + d] = f2bf((acc[m][n][j] + bv) * sc);
            }
        }
    }
}

// ---------------- output GEMM: fp32 out = A @ Wout + b ----------------
__global__ __launch_bounds__(256) void gemm_out_kernel(const u16* __restrict__ A, const u16* __restrict__ Bt,
                                                       const float* __restrict__ bias,
                                                       float* __restrict__ out) {
    __shared__ __align__(16) u16 As[128 * 32];
    __shared__ __align__(16) u16 Bs[128 * 32];
    int tid = threadIdx.x;
    int m0 = blockIdx.x * 128, n0 = blockIdx.y * 128;
    f32x4 acc[4][4];
    gemm_tile(A, Bt, m0, n0, acc, As, Bs, tid);

    int lane = tid & 63, wid = tid >> 6;
    int wr = wid >> 1, wc = wid & 1, g = lane >> 4, r = lane & 15;
#pragma unroll
    for (int m = 0; m < 4; m++) {
#pragma unroll
        for (int n = 0; n < 4; n++) {
            int col = n0 + wc * 64 + n * 16 + r;
            float bv = bias[col];
#pragma unroll
            for (int j = 0; j < 4; j++) {
                int row = m0 + wr * 64 + m * 16 + g * 4 + j;
                out[(size_t)row * 1024 + col] = acc[m][n][j] + bv;
            }
        }
    }
}

// ---------------- causal flash attention ----------------
// grid: (16, B*H), block 512 = 8 waves: rg = wid&3 (16-row group), kp = wid>>2
// (kv parity). Block does q-tiles (31-x) then (x): exactly 33 kv tiles total,
// uniform for EVERY block (no dependence on dispatch->CU mapping). Each wave
// handles kv = kp, kp+2, ...; kp=0/1 partials merged via LDS (flash combine).
// Swapped S^T = mfma(K, Q): lane (r,g) owns q = q0+rg*16+r, k = k0+nt*16+4g+j.
__global__ __launch_bounds__(512, 4) void attn_kernel(const u16* __restrict__ Q, const u16* __restrict__ K,
                                                      const u16* __restrict__ VT, u16* __restrict__ O) {
    __shared__ __align__(16) u16 Ps[8][16][72];     // per-wave P (q-major), padded
    __shared__ __align__(16) float Mrg[4][64][20];  // [rg][lane][o16, m, l, pad2]

    const int tid = threadIdx.x;
    const int lane = tid & 63, wid = tid >> 6;
    const int g = lane >> 4, r = lane & 15;
    const int rg = wid & 3, kp = wid >> 2;
    const int bh = blockIdx.y;
    const int b = bh >> 4, h = bh & 15;
    const u16* Qb  = Q  + (size_t)bh * T_SEQ * HD;
    const u16* Kb  = K  + (size_t)bh * T_SEQ * HD;
    const u16* VTb = VT + (size_t)bh * HD * T_SEQ;
    u16 (*myPs)[72] = Ps[wid];

    for (int pass = 0; pass < 2; ++pass) {
        const int qt = pass ? (int)blockIdx.x : 31 - (int)blockIdx.x;
        const int q0 = qt * 64;
        const int q  = q0 + rg * 16 + r;         // this lane's q row (fixed)

        // Q fragments (B-operand: col = lane%16 -> q, 8 contiguous d per lane)
        short8 qf0 = *(const short8*)&Qb[(size_t)q * HD + 8 * g];
        short8 qf1 = *(const short8*)&Qb[(size_t)q * HD + 32 + 8 * g];

        float mrun = -1e30f, srun = 0.f;
        f32x4 o[4];
#pragma unroll
        for (int dt = 0; dt < 4; dt++) o[dt] = (f32x4){0.f, 0.f, 0.f, 0.f};

        // preload first K tile for this parity (A-operand: row = lane%16 -> k)
        short8 kc0[4], kc1[4];
        if (kp <= qt) {
            const int kb0 = kp * 64;
#pragma unroll
            for (int nt = 0; nt < 4; nt++) {
                kc0[nt] = *(const short8*)&Kb[(size_t)(kb0 + nt * 16 + r) * HD + 8 * g];
                kc1[nt] = *(const short8*)&Kb[(size_t)(kb0 + nt * 16 + r) * HD + 32 + 8 * g];
            }
        }

        for (int kv = kp; kv <= qt; kv += 2) {
            const int k0 = kv * 64;

            // V^T fragments (A-operand for PV: row = d, contraction k)
            short8 vf0[4], vf1[4];
#pragma unroll
            for (int dt = 0; dt < 4; dt++) {
                vf0[dt] = *(const short8*)&VTb[(size_t)(dt * 16 + r) * T_SEQ + k0 + 8 * g];
                vf1[dt] = *(const short8*)&VTb[(size_t)(dt * 16 + r) * T_SEQ + k0 + 32 + 8 * g];
            }

            // S^T = K Q^T (Q pre-scaled by 1/8)
            f32x4 s[4];
            __builtin_amdgcn_s_setprio(1);
#pragma unroll
            for (int nt = 0; nt < 4; nt++) {
                f32x4 z = (f32x4){0.f, 0.f, 0.f, 0.f};
                z = __builtin_amdgcn_mfma_f32_16x16x32_bf16(kc0[nt], qf0, z, 0, 0, 0);
                z = __builtin_amdgcn_mfma_f32_16x16x32_bf16(kc1[nt], qf1, z, 0, 0, 0);
                s[nt] = z;
            }
            __builtin_amdgcn_s_setprio(0);

            // prefetch next K tile for this parity (hidden under softmax + PV)
            if (kv + 2 <= qt) {
                const int k1 = k0 + 128;
#pragma unroll
                for (int nt = 0; nt < 4; nt++) {
                    kc0[nt] = *(const short8*)&Kb[(size_t)(k1 + nt * 16 + r) * HD + 8 * g];
                    kc1[nt] = *(const short8*)&Kb[(size_t)(k1 + nt * 16 + r) * HD + 32 + 8 * g];
                }
            }

            // causal mask (diagonal tile only)
            if (kv == qt) {
#pragma unroll
                for (int nt = 0; nt < 4; nt++) {
                    int kb = k0 + nt * 16 + 4 * g;
#pragma unroll
                    for (int j = 0; j < 4; j++)
                        if (kb + j > q) s[nt][j] = -1e30f;
                }
            }

            // row max: 15 in-lane + 2 shuffle rounds (lane's q shared by r,r+16,r+32,r+48)
            float mt = s[0][0];
#pragma unroll
            for (int nt = 0; nt < 4; nt++)
#pragma unroll
                for (int j = 0; j < 4; j++) mt = fmaxf(mt, s[nt][j]);
            mt = fmaxf(mt, __shfl_xor(mt, 16));
            mt = fmaxf(mt, __shfl_xor(mt, 32));

            // online softmax (scalar state per lane)
            float mn = fmaxf(mrun, mt);
            float corr = __expf(mrun - mn);
            mrun = mn;
            float psum = 0.f;
#pragma unroll
            for (int nt = 0; nt < 4; nt++)
#pragma unroll
                for (int j = 0; j < 4; j++) {
                    float p = __expf(s[nt][j] - mn);
                    s[nt][j] = p;
                    psum += p;
                }
            psum += __shfl_xor(psum, 16);
            psum += __shfl_xor(psum, 32);
            srun = srun * corr + psum;
#pragma unroll
            for (int dt = 0; dt < 4; dt++)
#pragma unroll
                for (int j = 0; j < 4; j++) o[dt][j] *= corr;

            // P -> LDS packed (4x ds_write_b64), then B-operand fragments back
#pragma unroll
            for (int nt = 0; nt < 4; nt++) {
                ushort4 pk;
                pk.x = f2bf(s[nt][0]);
                pk.y = f2bf(s[nt][1]);
                pk.z = f2bf(s[nt][2]);
                pk.w = f2bf(s[nt][3]);
                *(ushort4*)&myPs[r][nt * 16 + 4 * g] = pk;
            }
            short8 pf0 = *(short8*)&myPs[r][8 * g];
            short8 pf1 = *(short8*)&myPs[r][32 + 8 * g];

            __builtin_amdgcn_s_setprio(1);
#pragma unroll
            for (int dt = 0; dt < 4; dt++) {
                o[dt] = __builtin_amdgcn_mfma_f32_16x16x32_bf16(vf0[dt], pf0, o[dt], 0, 0, 0);
                o[dt] = __builtin_amdgcn_mfma_f32_16x16x32_bf16(vf1[dt], pf1, o[dt], 0, 0, 0);
            }
            __builtin_amdgcn_s_setprio(0);
        }

        // -------- merge kv-parity partials (flash combine), then epilogue --------
        __syncthreads();                 // Mrg free (prev pass readers done)
        if (kp == 1) {
            float* mb = Mrg[rg][lane];
#pragma unroll
            for (int dt = 0; dt < 4; dt++) *(f32x4*)&mb[dt * 4] = o[dt];
            mb[16] = mrun;
            mb[17] = srun;
        }
        __syncthreads();
        if (kp == 0) {
            const float* mb = Mrg[rg][lane];
            float m1 = mb[16], l1 = mb[17];
            float mm = fmaxf(mrun, m1);
            float c0 = __expf(mrun - mm);
            float c1 = __expf(m1 - mm);
            float inv = 1.f / (srun * c0 + l1 * c1);
            float s0 = c0 * inv, s1 = c1 * inv;
#pragma unroll
            for (int dt = 0; dt < 4; dt++) {
                f32x4 o1 = *(const f32x4*)&mb[dt * 4];
                ushort4 pk;
                pk.x = f2bf(o[dt][0] * s0 + o1[0] * s1);
                pk.y = f2bf(o[dt][1] * s0 + o1[1] * s1);
                pk.z = f2bf(o[dt][2] * s0 + o1[2] * s1);
                pk.w = f2bf(o[dt][3] * s0 + o1[3] * s1);
                *(ushort4*)&O[(((size_t)(b * T_SEQ + q)) * NH + h) * HD + dt * 16 + 4 * g] = pk;
            }
        }
    }
}

extern "C" void kernel_launch(void* const* d_in, const int* in_sizes, int n_in,
                              void* d_out, int out_size, void* d_ws, size_t ws_size,
                              hipStream_t stream) {
    const float* x     = (const float*)d_in[0];
    const float* W_qkv = (const float*)d_in[1];
    const float* b_qkv = (const float*)d_in[2];
    const float* W_out = (const float*)d_in[3];
    const float* b_out = (const float*)d_in[4];
    float* out = (float*)d_out;

    char* ws = (char*)d_ws;
    u16* xb    = (u16*)(ws);
    u16* wqkvt = (u16*)(ws + 8388608);
    u16* woutt = (u16*)(ws + 14680064);
    u16* Qp    = (u16*)(ws + 16777216);
    u16* Kp    = (u16*)(ws + 25165824);
    u16* VTp   = (u16*)(ws + 33554432);
    u16* attnb = (u16*)(ws);   // alias xb (dead after gemm_qkv)

    cast_bf16_kernel<<<4096, 256, 0, stream>>>(x, xb, 1048576);
    transpose_cast_kernel<<<dim3(96, 32), dim3(32, 8), 0, stream>>>(W_qkv, wqkvt, 1024, 3072);
    transpose_cast_kernel<<<dim3(32, 32), dim3(32, 8), 0, stream>>>(W_out, woutt, 1024, 1024);
    gemm_qkv_kernel<<<dim3(32, 24), 256, 0, stream>>>(xb, wqkvt, b_qkv, Qp, Kp, VTp);
    attn_kernel<<<dim3(16, 32), 512, 0, stream>>>(Qp, Kp, VTp, attnb);
    gemm_out_kernel<<<dim3(32, 8), 256, 0, stream>>>(attnb, woutt, b_out, out);
}

// Round 5
// 139.124 us; speedup vs baseline: 2.5077x; 1.5248x over previous
//
#include <hip/hip_runtime.h>
#include <hip/hip_bf16.h>
#include <stdint.h>

typedef unsigned short u16;
typedef __attribute__((ext_vector_type(8))) short short8;
typedef __attribute__((ext_vector_type(4))) float f32x4;

#define T_SEQ 2048
#define EMB   1024
#define NH    16
#define HD    64

__device__ __forceinline__ u16 f2bf(float f) {
    union { float f; uint32_t u; } x; x.f = f;
    uint32_t u = x.u;
    uint32_t r = u + 0x7fffu + ((u >> 16) & 1u);   // RNE
    return (u16)(r >> 16);
}

// async global -> LDS, 16 bytes per lane (wave-uniform LDS base + lane*16)
__device__ __forceinline__ void gld16(const void* g, void* l) {
    __builtin_amdgcn_global_load_lds(
        (const __attribute__((address_space(1))) void*)g,
        (__attribute__((address_space(3))) void*)l, 16, 0, 0);
}

// ---------------- cast fp32 -> bf16 (vectorized) ----------------
__global__ __launch_bounds__(256) void cast_bf16_kernel(const float* __restrict__ in,
                                                        u16* __restrict__ out, int n4) {
    int i = blockIdx.x * 256 + threadIdx.x;
    if (i < n4) {
        float4 v = ((const float4*)in)[i];
        uint32_t p0 = (uint32_t)f2bf(v.x) | ((uint32_t)f2bf(v.y) << 16);
        uint32_t p1 = (uint32_t)f2bf(v.z) | ((uint32_t)f2bf(v.w) << 16);
        ((uint2*)out)[i] = make_uint2(p0, p1);
    }
}

// ---------------- transpose + cast: Wt[n][k] = bf16(W[k][n]) ----------------
__global__ __launch_bounds__(256) void transpose_cast_kernel(const float* __restrict__ W,
                                                             u16* __restrict__ Wt,
                                                             int K, int N) {
    __shared__ float tile[32][33];
    int n0 = blockIdx.x * 32, k0 = blockIdx.y * 32;
    int tx = threadIdx.x, ty = threadIdx.y;   // 32 x 8
#pragma unroll
    for (int i = 0; i < 4; i++)
        tile[ty + i * 8][tx] = W[(k0 + ty + i * 8) * N + n0 + tx];
    __syncthreads();
#pragma unroll
    for (int i = 0; i < 4; i++)
        Wt[(size_t)(n0 + ty + i * 8) * K + k0 + tx] = f2bf(tile[tx][ty + i * 8]);
}

// ---------------- 128x128 tile GEMM core (K=1024, BK=32, 4 waves) ----------------
__device__ __forceinline__ void gemm_tile(const u16* __restrict__ A, const u16* __restrict__ Bt,
                                          int m0, int n0, f32x4 (&acc)[4][4],
                                          u16* As, u16* Bs, int tid) {
    const int lane = tid & 63;
    const int wid  = tid >> 6;
    const int wr = wid >> 1, wc = wid & 1;
    const int g = lane >> 4, r = lane & 15;
#pragma unroll
    for (int m = 0; m < 4; m++)
#pragma unroll
        for (int n = 0; n < 4; n++) acc[m][n] = (f32x4){0.f, 0.f, 0.f, 0.f};

    for (int kk = 0; kk < 1024; kk += 32) {
        __syncthreads();
#pragma unroll
        for (int c = 0; c < 2; c++) {
            int ofs = tid * 16 + c * 4096;       // byte offset into 8KB tile
            int row = ofs >> 6;                  // row stride = 32 bf16 = 64B
            int kb  = (ofs & 63) >> 1;
            gld16(&A[(size_t)(m0 + row) * 1024 + kk + kb], &As[ofs >> 1]);
            gld16(&Bt[(size_t)(n0 + row) * 1024 + kk + kb], &Bs[ofs >> 1]);
        }
        __syncthreads();
        short8 af[4], bf[4];
#pragma unroll
        for (int m = 0; m < 4; m++) af[m] = *(short8*)&As[(wr * 64 + m * 16 + r) * 32 + g * 8];
#pragma unroll
        for (int n = 0; n < 4; n++) bf[n] = *(short8*)&Bs[(wc * 64 + n * 16 + r) * 32 + g * 8];
#pragma unroll
        for (int m = 0; m < 4; m++)
#pragma unroll
            for (int n = 0; n < 4; n++)
                acc[m][n] = __builtin_amdgcn_mfma_f32_16x16x32_bf16(af[m], bf[n], acc[m][n], 0, 0, 0);
    }
}

// ---------------- QKV GEMM: Q (pre-scaled by 1/8), K -> [B,H,T,D]; V -> VT [B,H,D,T] ----------------
__global__ __launch_bounds__(256) void gemm_qkv_kernel(const u16* __restrict__ A, const u16* __restrict__ Bt,
                                                       const float* __restrict__ bias,
                                                       u16* __restrict__ Qo, u16* __restrict__ Ko,
                                                       u16* __restrict__ VTo) {
    __shared__ __align__(16) u16 As[128 * 32];
    __shared__ __align__(16) u16 Bs[128 * 32];
    int tid = threadIdx.x;
    int m0 = blockIdx.x * 128, n0 = blockIdx.y * 128;
    f32x4 acc[4][4];
    gemm_tile(A, Bt, m0, n0, acc, As, Bs, tid);

    int lane = tid & 63, wid = tid >> 6;
    int wr = wid >> 1, wc = wid & 1, g = lane >> 4, r = lane & 15;
#pragma unroll
    for (int m = 0; m < 4; m++) {
#pragma unroll
        for (int n = 0; n < 4; n++) {
            int col = n0 + wc * 64 + n * 16 + r;     // [0,3072)
            float bv = bias[col];
            int which = col >> 10;
            int e = col & 1023;
            int h = e >> 6, d = e & 63;
            int row0 = m0 + wr * 64 + m * 16 + g * 4;   // token base, multiple of 4
            int b = row0 >> 11, t0 = row0 & 2047;
            if (which == 2) {
                ushort4 pk;
                pk.x = f2bf(acc[m][n][0] + bv);
                pk.y = f2bf(acc[m][n][1] + bv);
                pk.z = f2bf(acc[m][n][2] + bv);
                pk.w = f2bf(acc[m][n][3] + bv);
                *(ushort4*)&VTo[(((size_t)(b * NH + h)) * HD + d) * T_SEQ + t0] = pk;
            } else {
                u16* dst = which ? Ko : Qo;
                float sc = which ? 1.0f : 0.125f;     // fold 1/sqrt(D) into Q
#pragma unroll
                for (int j = 0; j < 4; j++)
                    dst[(((size_t)(b * NH + h)) * T_SEQ + t0 + j) * HD + d] = f2bf((acc[m][n][j] + bv) * sc);
            }
        }
    }
}

// ---------------- output GEMM: fp32 out = A @ Wout + b ----------------
__global__ __launch_bounds__(256) void gemm_out_kernel(const u16* __restrict__ A, const u16* __restrict__ Bt,
                                                       const float* __restrict__ bias,
                                                       float* __restrict__ out) {
    __shared__ __align__(16) u16 As[128 * 32];
    __shared__ __align__(16) u16 Bs[128 * 32];
    int tid = threadIdx.x;
    int m0 = blockIdx.x * 128, n0 = blockIdx.y * 128;
    f32x4 acc[4][4];
    gemm_tile(A, Bt, m0, n0, acc, As, Bs, tid);

    int lane = tid & 63, wid = tid >> 6;
    int wr = wid >> 1, wc = wid & 1, g = lane >> 4, r = lane & 15;
#pragma unroll
    for (int m = 0; m < 4; m++) {
#pragma unroll
        for (int n = 0; n < 4; n++) {
            int col = n0 + wc * 64 + n * 16 + r;
            float bv = bias[col];
#pragma unroll
            for (int j = 0; j < 4; j++) {
                int row = m0 + wr * 64 + m * 16 + g * 4 + j;
                out[(size_t)row * 1024 + col] = acc[m][n][j] + bv;
            }
        }
    }
}

// ---------------- causal flash attention ----------------
// grid: (16, B*H), block 256 = 4 waves, wave wid owns q-rows [q0+wid*16, +16).
// Block does q-tiles (31-x) then (x): exactly 33 kv tiles, uniform per block.
// K and V^T tiles staged in LDS (double-buffered, global_load_lds, XOR-swizzled
// via pre-swizzled global source), shared by all 4 waves. One barrier per tile.
// Swapped S^T = mfma(K, Q): lane (r,g) owns q = q0+wid*16+r, k = k0+nt*16+4g+j.
__global__ __launch_bounds__(256) void attn_kernel(const u16* __restrict__ Q, const u16* __restrict__ K,
                                                   const u16* __restrict__ VT, u16* __restrict__ O) {
    __shared__ __align__(16) u16 Kl[2][64 * 64];    // [buf][row][64d], 128B rows, swizzled
    __shared__ __align__(16) u16 Vl[2][64 * 64];    // [buf][d][64k], swizzled
    __shared__ __align__(16) u16 Ps[4][16][72];     // per-wave P (q-major), padded

    const int tid = threadIdx.x;
    const int lane = tid & 63, wid = tid >> 6;
    const int g = lane >> 4, r = lane & 15;
    const int rb = r & 7;
    const int bh = blockIdx.y;
    const int b = bh >> 4, h = bh & 15;
    const u16* Qb  = Q  + (size_t)bh * T_SEQ * HD;
    const u16* Kb  = K  + (size_t)bh * T_SEQ * HD;
    const u16* VTb = VT + (size_t)bh * HD * T_SEQ;
    u16 (*myPs)[72] = Ps[wid];

    // staging geometry: thread covers 16B chunk m of row srow0 and srow0+32;
    // source chunk pre-swizzled so that swizzled ds_read returns linear data.
    const int srow0 = tid >> 3;
    const int sm = (tid & 7) ^ (srow0 & 7);         // (srow0+32)&7 == srow0&7

    auto stage = [&](int buf, int k0) {
        char* kd = (char*)&Kl[buf][0] + tid * 16;
        char* vd = (char*)&Vl[buf][0] + tid * 16;
        gld16(&Kb[(size_t)(k0 + srow0) * HD + sm * 8], kd);
        gld16(&Kb[(size_t)(k0 + srow0 + 32) * HD + sm * 8], kd + 4096);
        gld16(&VTb[(size_t)srow0 * T_SEQ + k0 + sm * 8], vd);
        gld16(&VTb[(size_t)(srow0 + 32) * T_SEQ + k0 + sm * 8], vd + 4096);
    };
    // swizzled fragment reads: row-major [64][64] tile, chunk = (h*4+g) ^ (r&7)
#define KFRAG(nt, hh) (*(const short8*)((const char*)&Kl[cur][0] + ((nt) * 16 + r) * 128 + ((((hh) * 4 + g) ^ rb) << 4)))
#define VFRAG(dt, hh) (*(const short8*)((const char*)&Vl[cur][0] + ((dt) * 16 + r) * 128 + ((((hh) * 4 + g) ^ rb) << 4)))

    for (int pass = 0; pass < 2; ++pass) {
        const int qt = pass ? (int)blockIdx.x : 31 - (int)blockIdx.x;
        const int q0 = qt * 64;
        const int q  = q0 + wid * 16 + r;        // this lane's q row (fixed)

        if (pass) __syncthreads();               // buf0 readers from pass 0 done
        stage(0, q0 - q0);                       // stage kv tile 0 into buf 0
        // (argument is k0 = 0; kept explicit for clarity)

        // Q fragments (B-operand: col = lane%16 -> q, 8 contiguous d per lane)
        short8 qf0 = *(const short8*)&Qb[(size_t)q * HD + 8 * g];
        short8 qf1 = *(const short8*)&Qb[(size_t)q * HD + 32 + 8 * g];

        float mrun = -1e30f, srun = 0.f;
        f32x4 o[4];
#pragma unroll
        for (int dt = 0; dt < 4; dt++) o[dt] = (f32x4){0.f, 0.f, 0.f, 0.f};

        for (int kv = 0; kv <= qt; kv++) {
            const int cur = kv & 1;
            const int k0 = kv * 64;
            __syncthreads();                     // implicit vmcnt(0): buf[cur] staged
            if (kv < qt) stage(cur ^ 1, k0 + 64);

            // S^T = K Q^T (Q pre-scaled by 1/8)
            f32x4 s[4];
            __builtin_amdgcn_s_setprio(1);
#pragma unroll
            for (int nt = 0; nt < 4; nt++) {
                f32x4 z = (f32x4){0.f, 0.f, 0.f, 0.f};
                z = __builtin_amdgcn_mfma_f32_16x16x32_bf16(KFRAG(nt, 0), qf0, z, 0, 0, 0);
                z = __builtin_amdgcn_mfma_f32_16x16x32_bf16(KFRAG(nt, 1), qf1, z, 0, 0, 0);
                s[nt] = z;
            }
            __builtin_amdgcn_s_setprio(0);

            // causal mask (diagonal tile only)
            if (kv == qt) {
#pragma unroll
                for (int nt = 0; nt < 4; nt++) {
                    int kb = k0 + nt * 16 + 4 * g;
#pragma unroll
                    for (int j = 0; j < 4; j++)
                        if (kb + j > q) s[nt][j] = -1e30f;
                }
            }

            // row max: 15 in-lane + 2 shuffle rounds
            float mt = s[0][0];
#pragma unroll
            for (int nt = 0; nt < 4; nt++)
#pragma unroll
                for (int j = 0; j < 4; j++) mt = fmaxf(mt, s[nt][j]);
            mt = fmaxf(mt, __shfl_xor(mt, 16));
            mt = fmaxf(mt, __shfl_xor(mt, 32));

            // online softmax (scalar state per lane)
            float mn = fmaxf(mrun, mt);
            float corr = __expf(mrun - mn);
            mrun = mn;
            float psum = 0.f;
#pragma unroll
            for (int nt = 0; nt < 4; nt++)
#pragma unroll
                for (int j = 0; j < 4; j++) {
                    float p = __expf(s[nt][j] - mn);
                    s[nt][j] = p;
                    psum += p;
                }
            psum += __shfl_xor(psum, 16);
            psum += __shfl_xor(psum, 32);
            srun = srun * corr + psum;
#pragma unroll
            for (int dt = 0; dt < 4; dt++)
#pragma unroll
                for (int j = 0; j < 4; j++) o[dt][j] *= corr;

            // P -> LDS packed (4x ds_write_b64), then B-operand fragments back
#pragma unroll
            for (int nt = 0; nt < 4; nt++) {
                ushort4 pk;
                pk.x = f2bf(s[nt][0]);
                pk.y = f2bf(s[nt][1]);
                pk.z = f2bf(s[nt][2]);
                pk.w = f2bf(s[nt][3]);
                *(ushort4*)&myPs[r][nt * 16 + 4 * g] = pk;
            }
            short8 pf0 = *(short8*)&myPs[r][8 * g];
            short8 pf1 = *(short8*)&myPs[r][32 + 8 * g];

            __builtin_amdgcn_s_setprio(1);
#pragma unroll
            for (int dt = 0; dt < 4; dt++) {
                o[dt] = __builtin_amdgcn_mfma_f32_16x16x32_bf16(VFRAG(dt, 0), pf0, o[dt], 0, 0, 0);
                o[dt] = __builtin_amdgcn_mfma_f32_16x16x32_bf16(VFRAG(dt, 1), pf1, o[dt], 0, 0, 0);
            }
            __builtin_amdgcn_s_setprio(0);
        }

        // epilogue: O^T regs -> O[b][t][h][d], 4 consecutive d per 8B store
        float inv = 1.f / srun;
#pragma unroll
        for (int dt = 0; dt < 4; dt++) {
            ushort4 pk;
            pk.x = f2bf(o[dt][0] * inv);
            pk.y = f2bf(o[dt][1] * inv);
            pk.z = f2bf(o[dt][2] * inv);
            pk.w = f2bf(o[dt][3] * inv);
            *(ushort4*)&O[(((size_t)(b * T_SEQ + q)) * NH + h) * HD + dt * 16 + 4 * g] = pk;
        }
    }
#undef KFRAG
#undef VFRAG
}

extern "C" void kernel_launch(void* const* d_in, const int* in_sizes, int n_in,
                              void* d_out, int out_size, void* d_ws, size_t ws_size,
                              hipStream_t stream) {
    const float* x     = (const float*)d_in[0];
    const float* W_qkv = (const float*)d_in[1];
    const float* b_qkv = (const float*)d_in[2];
    const float* W_out = (const float*)d_in[3];
    const float* b_out = (const float*)d_in[4];
    float* out = (float*)d_out;

    char* ws = (char*)d_ws;
    u16* xb    = (u16*)(ws);
    u16* wqkvt = (u16*)(ws + 8388608);
    u16* woutt = (u16*)(ws + 14680064);
    u16* Qp    = (u16*)(ws + 16777216);
    u16* Kp    = (u16*)(ws + 25165824);
    u16* VTp   = (u16*)(ws + 33554432);
    u16* attnb = (u16*)(ws);   // alias xb (dead after gemm_qkv)

    cast_bf16_kernel<<<4096, 256, 0, stream>>>(x, xb, 1048576);
    transpose_cast_kernel<<<dim3(96, 32), dim3(32, 8), 0, stream>>>(W_qkv, wqkvt, 1024, 3072);
    transpose_cast_kernel<<<dim3(32, 32), dim3(32, 8), 0, stream>>>(W_out, woutt, 1024, 1024);
    gemm_qkv_kernel<<<dim3(32, 24), 256, 0, stream>>>(xb, wqkvt, b_qkv, Qp, Kp, VTp);
    attn_kernel<<<dim3(16, 32), 256, 0, stream>>>(Qp, Kp, VTp, attnb);
    gemm_out_kernel<<<dim3(32, 8), 256, 0, stream>>>(attnb, woutt, b_out, out);
}

// Round 6
// 135.440 us; speedup vs baseline: 2.5759x; 1.0272x over previous
//
#include <hip/hip_runtime.h>
#include <hip/hip_bf16.h>
#include <stdint.h>

typedef unsigned short u16;
typedef __attribute__((ext_vector_type(8))) short short8;
typedef __attribute__((ext_vector_type(4))) float f32x4;

#define T_SEQ 2048
#define EMB   1024
#define NH    16
#define HD    64

__device__ __forceinline__ u16 f2bf(float f) {
    union { float f; uint32_t u; } x; x.f = f;
    uint32_t u = x.u;
    uint32_t r = u + 0x7fffu + ((u >> 16) & 1u);   // RNE
    return (u16)(r >> 16);
}

// packed fp32x2 -> bf16x2 (RNE), single instruction (T12 recipe)
__device__ __forceinline__ uint32_t cvtpk(float a, float b) {
    uint32_t r;
    asm("v_cvt_pk_bf16_f32 %0, %1, %2" : "=v"(r) : "v"(a), "v"(b));
    return r;
}

// async global -> LDS, 16 bytes per lane (wave-uniform LDS base + lane*16)
__device__ __forceinline__ void gld16(const void* g, void* l) {
    __builtin_amdgcn_global_load_lds(
        (const __attribute__((address_space(1))) void*)g,
        (__attribute__((address_space(3))) void*)l, 16, 0, 0);
}

// ---------------- cast fp32 -> bf16 (vectorized) ----------------
__global__ __launch_bounds__(256) void cast_bf16_kernel(const float* __restrict__ in,
                                                        u16* __restrict__ out, int n4) {
    int i = blockIdx.x * 256 + threadIdx.x;
    if (i < n4) {
        float4 v = ((const float4*)in)[i];
        uint32_t p0 = (uint32_t)f2bf(v.x) | ((uint32_t)f2bf(v.y) << 16);
        uint32_t p1 = (uint32_t)f2bf(v.z) | ((uint32_t)f2bf(v.w) << 16);
        ((uint2*)out)[i] = make_uint2(p0, p1);
    }
}

// ---------------- transpose + cast: Wt[n][k] = bf16(W[k][n]) ----------------
__global__ __launch_bounds__(256) void transpose_cast_kernel(const float* __restrict__ W,
                                                             u16* __restrict__ Wt,
                                                             int K, int N) {
    __shared__ float tile[32][33];
    int n0 = blockIdx.x * 32, k0 = blockIdx.y * 32;
    int tx = threadIdx.x, ty = threadIdx.y;   // 32 x 8
#pragma unroll
    for (int i = 0; i < 4; i++)
        tile[ty + i * 8][tx] = W[(k0 + ty + i * 8) * N + n0 + tx];
    __syncthreads();
#pragma unroll
    for (int i = 0; i < 4; i++)
        Wt[(size_t)(n0 + ty + i * 8) * K + k0 + tx] = f2bf(tile[tx][ty + i * 8]);
}

// ---------------- 128x128 tile GEMM core (K=1024, BK=32, 4 waves) ----------------
__device__ __forceinline__ void gemm_tile(const u16* __restrict__ A, const u16* __restrict__ Bt,
                                          int m0, int n0, f32x4 (&acc)[4][4],
                                          u16* As, u16* Bs, int tid) {
    const int lane = tid & 63;
    const int wid  = tid >> 6;
    const int wr = wid >> 1, wc = wid & 1;
    const int g = lane >> 4, r = lane & 15;
#pragma unroll
    for (int m = 0; m < 4; m++)
#pragma unroll
        for (int n = 0; n < 4; n++) acc[m][n] = (f32x4){0.f, 0.f, 0.f, 0.f};

    for (int kk = 0; kk < 1024; kk += 32) {
        __syncthreads();
#pragma unroll
        for (int c = 0; c < 2; c++) {
            int ofs = tid * 16 + c * 4096;       // byte offset into 8KB tile
            int row = ofs >> 6;                  // row stride = 32 bf16 = 64B
            int kb  = (ofs & 63) >> 1;
            gld16(&A[(size_t)(m0 + row) * 1024 + kk + kb], &As[ofs >> 1]);
            gld16(&Bt[(size_t)(n0 + row) * 1024 + kk + kb], &Bs[ofs >> 1]);
        }
        __syncthreads();
        short8 af[4], bf[4];
#pragma unroll
        for (int m = 0; m < 4; m++) af[m] = *(short8*)&As[(wr * 64 + m * 16 + r) * 32 + g * 8];
#pragma unroll
        for (int n = 0; n < 4; n++) bf[n] = *(short8*)&Bs[(wc * 64 + n * 16 + r) * 32 + g * 8];
#pragma unroll
        for (int m = 0; m < 4; m++)
#pragma unroll
            for (int n = 0; n < 4; n++)
                acc[m][n] = __builtin_amdgcn_mfma_f32_16x16x32_bf16(af[m], bf[n], acc[m][n], 0, 0, 0);
    }
}

// ---------------- QKV GEMM: Q pre-scaled by 0.125*log2(e), K -> [B,H,T,D]; V -> VT [B,H,D,T] ----
__global__ __launch_bounds__(256) void gemm_qkv_kernel(const u16* __restrict__ A, const u16* __restrict__ Bt,
                                                       const float* __restrict__ bias,
                                                       u16* __restrict__ Qo, u16* __restrict__ Ko,
                                                       u16* __restrict__ VTo) {
    __shared__ __align__(16) u16 As[128 * 32];
    __shared__ __align__(16) u16 Bs[128 * 32];
    int tid = threadIdx.x;
    int m0 = blockIdx.x * 128, n0 = blockIdx.y * 128;
    f32x4 acc[4][4];
    gemm_tile(A, Bt, m0, n0, acc, As, Bs, tid);

    int lane = tid & 63, wid = tid >> 6;
    int wr = wid >> 1, wc = wid & 1, g = lane >> 4, r = lane & 15;
#pragma unroll
    for (int m = 0; m < 4; m++) {
#pragma unroll
        for (int n = 0; n < 4; n++) {
            int col = n0 + wc * 64 + n * 16 + r;     // [0,3072)
            float bv = bias[col];
            int which = col >> 10;
            int e = col & 1023;
            int h = e >> 6, d = e & 63;
            int row0 = m0 + wr * 64 + m * 16 + g * 4;   // token base, multiple of 4
            int b = row0 >> 11, t0 = row0 & 2047;
            if (which == 2) {
                ushort4 pk;
                pk.x = f2bf(acc[m][n][0] + bv);
                pk.y = f2bf(acc[m][n][1] + bv);
                pk.z = f2bf(acc[m][n][2] + bv);
                pk.w = f2bf(acc[m][n][3] + bv);
                *(ushort4*)&VTo[(((size_t)(b * NH + h)) * HD + d) * T_SEQ + t0] = pk;
            } else {
                u16* dst = which ? Ko : Qo;
                // Q: fold 1/sqrt(D) AND log2(e) so attn uses exp2 directly
                float sc = which ? 1.0f : 0.18033688011112042f;
#pragma unroll
                for (int j = 0; j < 4; j++)
                    dst[(((size_t)(b * NH + h)) * T_SEQ + t0 + j) * HD + d] = f2bf((acc[m][n][j] + bv) * sc);
            }
        }
    }
}

// ---------------- output GEMM: fp32 out = A @ Wout + b ----------------
__global__ __launch_bounds__(256) void gemm_out_kernel(const u16* __restrict__ A, const u16* __restrict__ Bt,
                                                       const float* __restrict__ bias,
                                                       float* __restrict__ out) {
    __shared__ __align__(16) u16 As[128 * 32];
    __shared__ __align__(16) u16 Bs[128 * 32];
    int tid = threadIdx.x;
    int m0 = blockIdx.x * 128, n0 = blockIdx.y * 128;
    f32x4 acc[4][4];
    gemm_tile(A, Bt, m0, n0, acc, As, Bs, tid);

    int lane = tid & 63, wid = tid >> 6;
    int wr = wid >> 1, wc = wid & 1, g = lane >> 4, r = lane & 15;
#pragma unroll
    for (int m = 0; m < 4; m++) {
#pragma unroll
        for (int n = 0; n < 4; n++) {
            int col = n0 + wc * 64 + n * 16 + r;
            float bv = bias[col];
#pragma unroll
            for (int j = 0; j < 4; j++) {
                int row = m0 + wr * 64 + m * 16 + g * 4 + j;
                out[(size_t)row * 1024 + col] = acc[m][n][j] + bv;
            }
        }
    }
}

// ---------------- causal flash attention ----------------
// grid: (512) flat, XCD-swizzled: bh = ((bid>>7)<<3)|(bid&7) so all 16 blocks of a
// head land on one XCD's L2 (4 heads x 768KB = 3MB < 4MB). x = (bid>>3)&15.
// Block = 512 threads = 8 waves: rg = wid&3 (16 q-rows), kh = wid>>2 (32 k-cols).
// Each block does q-tiles (31-x, x): exactly 33 kv tiles, uniform per block.
// K/V^T staged in LDS dbuf (swizzled global_load_lds), shared by all 8 waves.
// Swapped S^T = mfma(K,Q): lane (r,g) owns q = q0+rg*16+r, k = k0+kh*32+nt*16+4g+j.
// kh=0/1 keep independent online-softmax state; merged once per pass via LDS.
__global__ __launch_bounds__(512) void attn_kernel(const u16* __restrict__ Q, const u16* __restrict__ K,
                                                   const u16* __restrict__ VT, u16* __restrict__ O) {
    __shared__ __align__(16) u16 Kl[2][64 * 64];    // [buf][k-row][64d], swizzled
    __shared__ __align__(16) u16 Vl[2][64 * 64];    // [buf][d][64k], swizzled
    __shared__ __align__(16) u16 Ps[8][16][40];     // per-wave P (q-major, 32k), 80B rows

    const int tid = threadIdx.x;
    const int lane = tid & 63, wid = tid >> 6;
    const int g = lane >> 4, r = lane & 15;
    const int rg = wid & 3, kh = wid >> 2;
    const int bid = blockIdx.x;
    const int bh = ((bid >> 7) << 3) | (bid & 7);
    const int xb = (bid >> 3) & 15;
    const int b = bh >> 4, h = bh & 15;
    const u16* Qb  = Q  + (size_t)bh * T_SEQ * HD;
    const u16* Kb  = K  + (size_t)bh * T_SEQ * HD;
    const u16* VTb = VT + (size_t)bh * HD * T_SEQ;
    u16 (*myPs)[40] = Ps[wid];
    const float NEGINF = -__builtin_inff();

    // staging: 512 threads cover 64 rows x 8 chunks of 16B for K and V each;
    // source chunk pre-swizzled so swizzled ds_read returns linear data.
    const int srow = tid >> 3;
    const int sm = (tid & 7) ^ (srow & 7);
    auto stage = [&](int buf, int k0) {
        gld16(&Kb[(size_t)(k0 + srow) * HD + sm * 8], (char*)&Kl[buf][0] + tid * 16);
        gld16(&VTb[(size_t)srow * T_SEQ + k0 + sm * 8], (char*)&Vl[buf][0] + tid * 16);
    };
#define KFRAG(nt, hh) (*(const short8*)((const char*)&Kl[cur][0] + ((nt) * 16 + r) * 128 + ((((hh) * 4 + g) ^ (r & 7)) << 4)))
#define VFRAG(dt, hh) (*(const short8*)((const char*)&Vl[cur][0] + ((dt) * 16 + r) * 128 + ((((hh) * 4 + g) ^ (r & 7)) << 4)))

    for (int pass = 0; pass < 2; ++pass) {
        const int qt = pass ? xb : 31 - xb;
        const int q0 = qt * 64;
        const int q  = q0 + rg * 16 + r;         // this lane's q row (fixed)

        if (pass) __syncthreads();               // pass-0 merge reads done
        stage(0, 0);

        // Q fragments (B-operand: col = lane%16 -> q, 8 contiguous d per lane)
        short8 qf0 = *(const short8*)&Qb[(size_t)q * HD + 8 * g];
        short8 qf1 = *(const short8*)&Qb[(size_t)q * HD + 32 + 8 * g];

        float mrun = -1e30f, srun = 0.f;
        f32x4 o[4];
#pragma unroll
        for (int dt = 0; dt < 4; dt++) o[dt] = (f32x4){0.f, 0.f, 0.f, 0.f};

        for (int kv = 0; kv <= qt; kv++) {
            const int cur = kv & 1;
            const int k0 = kv * 64;
            __syncthreads();                     // buf[cur] staged (vmcnt drained)
            if (kv < qt) stage(cur ^ 1, k0 + 64);

            // S^T = K Q^T over this wave's 32 k-cols (Q pre-scaled, log2 domain)
            f32x4 s[2];
            __builtin_amdgcn_s_setprio(1);
#pragma unroll
            for (int nt = 0; nt < 2; nt++) {
                f32x4 z = (f32x4){0.f, 0.f, 0.f, 0.f};
                z = __builtin_amdgcn_mfma_f32_16x16x32_bf16(KFRAG(kh * 2 + nt, 0), qf0, z, 0, 0, 0);
                z = __builtin_amdgcn_mfma_f32_16x16x32_bf16(KFRAG(kh * 2 + nt, 1), qf1, z, 0, 0, 0);
                s[nt] = z;
            }
            __builtin_amdgcn_s_setprio(0);

            // causal mask (diagonal tile only)
            if (kv == qt) {
#pragma unroll
                for (int nt = 0; nt < 2; nt++) {
                    int kb = k0 + kh * 32 + nt * 16 + 4 * g;
#pragma unroll
                    for (int j = 0; j < 4; j++)
                        if (kb + j > q) s[nt][j] = NEGINF;
                }
            }

            // tile max: 7 in-lane + 2 shuffle rounds (quad r, r+16, r+32, r+48)
            float mt = fmaxf(fmaxf(fmaxf(s[0][0], s[0][1]), fmaxf(s[0][2], s[0][3])),
                             fmaxf(fmaxf(s[1][0], s[1][1]), fmaxf(s[1][2], s[1][3])));
            mt = fmaxf(mt, __shfl_xor(mt, 16));
            mt = fmaxf(mt, __shfl_xor(mt, 32));

            // defer-max: rescale only when tile max exceeds running max by >8 (log2)
            if (mt > mrun + 8.f) {
                float corr = __builtin_exp2f(mrun - mt);
                mrun = mt;
                srun *= corr;
#pragma unroll
                for (int dt = 0; dt < 4; dt++)
#pragma unroll
                    for (int j = 0; j < 4; j++) o[dt][j] *= corr;
            }

            float psum = 0.f;
#pragma unroll
            for (int nt = 0; nt < 2; nt++)
#pragma unroll
                for (int j = 0; j < 4; j++) {
                    float p = __builtin_exp2f(s[nt][j] - mrun);
                    s[nt][j] = p;
                    psum += p;
                }
            psum += __shfl_xor(psum, 16);
            psum += __shfl_xor(psum, 32);
            srun += psum;

            // P -> LDS packed via cvt_pk (2x ds_write_b64), fragments back
#pragma unroll
            for (int nt = 0; nt < 2; nt++) {
                uint2 pk;
                pk.x = cvtpk(s[nt][0], s[nt][1]);
                pk.y = cvtpk(s[nt][2], s[nt][3]);
                *(uint2*)&myPs[r][nt * 16 + 4 * g] = pk;
            }
            short8 pf = *(short8*)&myPs[r][8 * g];

            __builtin_amdgcn_s_setprio(1);
#pragma unroll
            for (int dt = 0; dt < 4; dt++)
                o[dt] = __builtin_amdgcn_mfma_f32_16x16x32_bf16(VFRAG(dt, kh), pf, o[dt], 0, 0, 0);
            __builtin_amdgcn_s_setprio(0);
        }

        // -------- merge kh partials (flash combine, log2 domain) + epilogue --------
        __syncthreads();                         // all tile compute done; Kl reusable
        float* mb = ((float*)&Kl[0][0]) + ((rg * 64 + lane) * 18);
        if (kh) {
#pragma unroll
            for (int dt = 0; dt < 4; dt++) *(f32x4*)&mb[dt * 4] = o[dt];
            mb[16] = mrun;
            mb[17] = srun;
        }
        __syncthreads();
        if (!kh) {
            float m1 = mb[16], l1 = mb[17];
            float mm = fmaxf(mrun, m1);
            float c0 = __builtin_exp2f(mrun - mm);
            float c1 = __builtin_exp2f(m1 - mm);
            float inv = 1.f / (srun * c0 + l1 * c1);
            float s0 = c0 * inv, s1 = c1 * inv;
#pragma unroll
            for (int dt = 0; dt < 4; dt++) {
                f32x4 o1 = *(const f32x4*)&mb[dt * 4];
                ushort4 pk;
                pk.x = f2bf(o[dt][0] * s0 + o1[0] * s1);
                pk.y = f2bf(o[dt][1] * s0 + o1[1] * s1);
                pk.z = f2bf(o[dt][2] * s0 + o1[2] * s1);
                pk.w = f2bf(o[dt][3] * s0 + o1[3] * s1);
                *(ushort4*)&O[(((size_t)(b * T_SEQ + q)) * NH + h) * HD + dt * 16 + 4 * g] = pk;
            }
        }
    }
#undef KFRAG
#undef VFRAG
}

extern "C" void kernel_launch(void* const* d_in, const int* in_sizes, int n_in,
                              void* d_out, int out_size, void* d_ws, size_t ws_size,
                              hipStream_t stream) {
    const float* x     = (const float*)d_in[0];
    const float* W_qkv = (const float*)d_in[1];
    const float* b_qkv = (const float*)d_in[2];
    const float* W_out = (const float*)d_in[3];
    const float* b_out = (const float*)d_in[4];
    float* out = (float*)d_out;

    char* ws = (char*)d_ws;
    u16* xb    = (u16*)(ws);
    u16* wqkvt = (u16*)(ws + 8388608);
    u16* woutt = (u16*)(ws + 14680064);
    u16* Qp    = (u16*)(ws + 16777216);
    u16* Kp    = (u16*)(ws + 25165824);
    u16* VTp   = (u16*)(ws + 33554432);
    u16* attnb = (u16*)(ws);   // alias xb (dead after gemm_qkv)

    cast_bf16_kernel<<<4096, 256, 0, stream>>>(x, xb, 1048576);
    transpose_cast_kernel<<<dim3(96, 32), dim3(32, 8), 0, stream>>>(W_qkv, wqkvt, 1024, 3072);
    transpose_cast_kernel<<<dim3(32, 32), dim3(32, 8), 0, stream>>>(W_out, woutt, 1024, 1024);
    gemm_qkv_kernel<<<dim3(32, 24), 256, 0, stream>>>(xb, wqkvt, b_qkv, Qp, Kp, VTp);
    attn_kernel<<<512, 512, 0, stream>>>(Qp, Kp, VTp, attnb);
    gemm_out_kernel<<<dim3(32, 8), 256, 0, stream>>>(attnb, woutt, b_out, out);
}

// Round 7
// 130.310 us; speedup vs baseline: 2.6774x; 1.0394x over previous
//
#include <hip/hip_runtime.h>
#include <hip/hip_bf16.h>
#include <stdint.h>

typedef unsigned short u16;
typedef __attribute__((ext_vector_type(8))) short short8;
typedef __attribute__((ext_vector_type(4))) float f32x4;

#define T_SEQ 2048
#define EMB   1024
#define NH    16
#define HD    64

__device__ __forceinline__ u16 f2bf(float f) {
    union { float f; uint32_t u; } x; x.f = f;
    uint32_t u = x.u;
    uint32_t r = u + 0x7fffu + ((u >> 16) & 1u);   // RNE
    return (u16)(r >> 16);
}

// packed fp32x2 -> bf16x2 (RNE), single instruction; lo = first arg (verified R5)
__device__ __forceinline__ uint32_t cvtpk(float a, float b) {
    uint32_t r;
    asm("v_cvt_pk_bf16_f32 %0, %1, %2" : "=v"(r) : "v"(a), "v"(b));
    return r;
}

// async global -> LDS, 16 bytes per lane (wave-uniform LDS base + lane*16)
__device__ __forceinline__ void gld16(const void* g, void* l) {
    __builtin_amdgcn_global_load_lds(
        (const __attribute__((address_space(1))) void*)g,
        (__attribute__((address_space(3))) void*)l, 16, 0, 0);
}

// ---------------- cast fp32 -> bf16 (vectorized) ----------------
__global__ __launch_bounds__(256) void cast_bf16_kernel(const float* __restrict__ in,
                                                        u16* __restrict__ out, int n4) {
    int i = blockIdx.x * 256 + threadIdx.x;
    if (i < n4) {
        float4 v = ((const float4*)in)[i];
        ((uint2*)out)[i] = make_uint2(cvtpk(v.x, v.y), cvtpk(v.z, v.w));
    }
}

// ---------------- transpose + cast: Wt[n][k] = bf16(W[k][n]) ----------------
__global__ __launch_bounds__(256) void transpose_cast_kernel(const float* __restrict__ W,
                                                             u16* __restrict__ Wt,
                                                             int K, int N) {
    __shared__ float tile[32][33];
    int n0 = blockIdx.x * 32, k0 = blockIdx.y * 32;
    int tx = threadIdx.x, ty = threadIdx.y;   // 32 x 8
#pragma unroll
    for (int i = 0; i < 4; i++)
        tile[ty + i * 8][tx] = W[(k0 + ty + i * 8) * N + n0 + tx];
    __syncthreads();
#pragma unroll
    for (int i = 0; i < 4; i++)
        Wt[(size_t)(n0 + ty + i * 8) * K + k0 + tx] = f2bf(tile[tx][ty + i * 8]);
}

// ---------------- 128x128 tile GEMM core (K=1024, BK=32, 4 waves) ----------------
// Double-buffered (T3 minimal): barrier -> stage(next) -> compute(cur).
// As/Bs: [2][128*32] u16 (8KB per buffer each).
__device__ __forceinline__ void gemm_tile(const u16* __restrict__ A, const u16* __restrict__ Bt,
                                          int m0, int n0, f32x4 (&acc)[4][4],
                                          u16* As, u16* Bs, int tid) {
    const int lane = tid & 63;
    const int wid  = tid >> 6;
    const int wr = wid >> 1, wc = wid & 1;
    const int g = lane >> 4, r = lane & 15;
#pragma unroll
    for (int m = 0; m < 4; m++)
#pragma unroll
        for (int n = 0; n < 4; n++) acc[m][n] = (f32x4){0.f, 0.f, 0.f, 0.f};

    // staging geometry: thread covers 16B of row (tid/4) and (tid/4 + 64)
    const int srow = tid >> 2;
    const int skb  = (tid & 3) * 8;
    const u16* ag = A  + (size_t)(m0 + srow) * 1024 + skb;
    const u16* bg = Bt + (size_t)(n0 + srow) * 1024 + skb;
    char* asl = (char*)As + tid * 16;
    char* bsl = (char*)Bs + tid * 16;

    auto stage = [&](int buf, int kk) {
        gld16(ag + kk,             asl + buf * 8192);
        gld16(ag + kk + 64 * 1024, asl + buf * 8192 + 4096);
        gld16(bg + kk,             bsl + buf * 8192);
        gld16(bg + kk + 64 * 1024, bsl + buf * 8192 + 4096);
    };

    stage(0, 0);
    for (int it = 0; it < 32; ++it) {
        const int cur = it & 1;
        __syncthreads();                      // buf[cur] staged (barrier drains vmcnt)
        if (it < 31) stage(cur ^ 1, (it + 1) * 32);
        const u16* as = As + cur * 4096;
        const u16* bs = Bs + cur * 4096;
        short8 af[4], bf[4];
#pragma unroll
        for (int m = 0; m < 4; m++) af[m] = *(const short8*)&as[(wr * 64 + m * 16 + r) * 32 + g * 8];
#pragma unroll
        for (int n = 0; n < 4; n++) bf[n] = *(const short8*)&bs[(wc * 64 + n * 16 + r) * 32 + g * 8];
#pragma unroll
        for (int m = 0; m < 4; m++)
#pragma unroll
            for (int n = 0; n < 4; n++)
                acc[m][n] = __builtin_amdgcn_mfma_f32_16x16x32_bf16(af[m], bf[n], acc[m][n], 0, 0, 0);
    }
}

// ---------------- QKV GEMM: Q pre-scaled by 0.125*log2(e), K -> [B,H,T,D]; V -> VT [B,H,D,T] ----
__global__ __launch_bounds__(256) void gemm_qkv_kernel(const u16* __restrict__ A, const u16* __restrict__ Bt,
                                                       const float* __restrict__ bias,
                                                       u16* __restrict__ Qo, u16* __restrict__ Ko,
                                                       u16* __restrict__ VTo) {
    __shared__ __align__(16) u16 As[2][128 * 32];
    __shared__ __align__(16) u16 Bs[2][128 * 32];
    int tid = threadIdx.x;
    int m0 = blockIdx.x * 128, n0 = blockIdx.y * 128;
    f32x4 acc[4][4];
    gemm_tile(A, Bt, m0, n0, acc, &As[0][0], &Bs[0][0], tid);

    int lane = tid & 63, wid = tid >> 6;
    int wr = wid >> 1, wc = wid & 1, g = lane >> 4, r = lane & 15;
#pragma unroll
    for (int m = 0; m < 4; m++) {
#pragma unroll
        for (int n = 0; n < 4; n++) {
            int col = n0 + wc * 64 + n * 16 + r;     // [0,3072)
            float bv = bias[col];
            int which = col >> 10;
            int e = col & 1023;
            int h = e >> 6, d = e & 63;
            int row0 = m0 + wr * 64 + m * 16 + g * 4;   // token base, multiple of 4
            int b = row0 >> 11, t0 = row0 & 2047;
            if (which == 2) {
                uint2 pk;
                pk.x = cvtpk(acc[m][n][0] + bv, acc[m][n][1] + bv);
                pk.y = cvtpk(acc[m][n][2] + bv, acc[m][n][3] + bv);
                *(uint2*)&VTo[(((size_t)(b * NH + h)) * HD + d) * T_SEQ + t0] = pk;
            } else {
                u16* dst = which ? Ko : Qo;
                // Q: fold 1/sqrt(D) AND log2(e) so attn uses exp2 directly
                float sc = which ? 1.0f : 0.18033688011112042f;
#pragma unroll
                for (int j = 0; j < 4; j++)
                    dst[(((size_t)(b * NH + h)) * T_SEQ + t0 + j) * HD + d] = f2bf((acc[m][n][j] + bv) * sc);
            }
        }
    }
}

// ---------------- output GEMM: fp32 out = A @ Wout + b ----------------
__global__ __launch_bounds__(256) void gemm_out_kernel(const u16* __restrict__ A, const u16* __restrict__ Bt,
                                                       const float* __restrict__ bias,
                                                       float* __restrict__ out) {
    __shared__ __align__(16) u16 As[2][128 * 32];
    __shared__ __align__(16) u16 Bs[2][128 * 32];
    int tid = threadIdx.x;
    int m0 = blockIdx.x * 128, n0 = blockIdx.y * 128;
    f32x4 acc[4][4];
    gemm_tile(A, Bt, m0, n0, acc, &As[0][0], &Bs[0][0], tid);

    int lane = tid & 63, wid = tid >> 6;
    int wr = wid >> 1, wc = wid & 1, g = lane >> 4, r = lane & 15;
#pragma unroll
    for (int m = 0; m < 4; m++) {
#pragma unroll
        for (int n = 0; n < 4; n++) {
            int col = n0 + wc * 64 + n * 16 + r;
            float bv = bias[col];
#pragma unroll
            for (int j = 0; j < 4; j++) {
                int row = m0 + wr * 64 + m * 16 + g * 4 + j;
                out[(size_t)row * 1024 + col] = acc[m][n][j] + bv;
            }
        }
    }
}

// ---------------- causal flash attention ----------------
// grid: (512) flat, XCD-swizzled: bh = ((bid>>7)<<3)|(bid&7); x = (bid>>3)&15.
// Block = 512 threads = 8 waves: rg = wid&3 (16 q-rows), kh = wid>>2 (32 k-cols).
// Block does q-tiles (31-x, x): exactly 33 kv tiles, uniform per block.
// K/V^T staged in LDS dbuf (swizzled global_load_lds); swapped S^T = mfma(K,Q).
// Row-sum via ones-MFMA (no psum shuffles); kh partials merged once per pass.
__global__ __launch_bounds__(512) void attn_kernel(const u16* __restrict__ Q, const u16* __restrict__ K,
                                                   const u16* __restrict__ VT, u16* __restrict__ O) {
    __shared__ __align__(16) u16 Kl[2][64 * 64];    // [buf][k-row][64d], swizzled
    __shared__ __align__(16) u16 Vl[2][64 * 64];    // [buf][d][64k], swizzled
    __shared__ __align__(16) u16 Ps[8][16][40];     // per-wave P (q-major, 32k), 80B rows

    const int tid = threadIdx.x;
    const int lane = tid & 63, wid = tid >> 6;
    const int g = lane >> 4, r = lane & 15;
    const int rg = wid & 3, kh = wid >> 2;
    const int bid = blockIdx.x;
    const int bh = ((bid >> 7) << 3) | (bid & 7);
    const int xb = (bid >> 3) & 15;
    const int b = bh >> 4, h = bh & 15;
    const u16* Qb  = Q  + (size_t)bh * T_SEQ * HD;
    const u16* Kb  = K  + (size_t)bh * T_SEQ * HD;
    const u16* VTb = VT + (size_t)bh * HD * T_SEQ;
    u16 (*myPs)[40] = Ps[wid];
    const float NEGINF = -__builtin_inff();

    // hoisted lane-constant LDS read offsets (swizzled)
    int koff[2][2], voff[4];
#pragma unroll
    for (int nt = 0; nt < 2; nt++)
#pragma unroll
        for (int hh = 0; hh < 2; hh++)
            koff[nt][hh] = ((kh * 2 + nt) * 16 + r) * 128 + ((((hh * 4 + g) ^ (r & 7)) << 4));
#pragma unroll
    for (int dt = 0; dt < 4; dt++)
        voff[dt] = (dt * 16 + r) * 128 + ((((kh * 4 + g) ^ (r & 7)) << 4));

    // hoisted staging addresses (vary only by k0 / buf)
    const int srow = tid >> 3;
    const int sm = (tid & 7) ^ (srow & 7);
    const u16* kgp = Kb + srow * HD + sm * 8;
    const u16* vgp = VTb + (size_t)srow * T_SEQ + sm * 8;
    char* kld = (char*)Kl + tid * 16;
    char* vld = (char*)Vl + tid * 16;
    auto stage = [&](int buf, int k0) {
        gld16(kgp + (size_t)k0 * HD, kld + (buf << 13));
        gld16(vgp + k0, vld + (buf << 13));
    };

    short8 onesf;
#pragma unroll
    for (int i = 0; i < 8; i++) onesf[i] = (short)0x3F80;   // bf16 1.0

    for (int pass = 0; pass < 2; ++pass) {
        const int qt = pass ? xb : 31 - xb;
        const int q0 = qt * 64;
        const int q  = q0 + rg * 16 + r;         // this lane's q row (fixed)

        if (pass) __syncthreads();               // pass-0 merge reads done
        stage(0, 0);

        // Q fragments (B-operand: col = lane%16 -> q, 8 contiguous d per lane)
        short8 qf0 = *(const short8*)&Qb[(size_t)q * HD + 8 * g];
        short8 qf1 = *(const short8*)&Qb[(size_t)q * HD + 32 + 8 * g];

        float mrun = -1e30f, srun = 0.f;
        f32x4 o[4];
#pragma unroll
        for (int dt = 0; dt < 4; dt++) o[dt] = (f32x4){0.f, 0.f, 0.f, 0.f};

        for (int kv = 0; kv <= qt; kv++) {
            const int cur = kv & 1;
            const int k0 = kv * 64;
            __syncthreads();                     // buf[cur] staged (vmcnt drained)
            if (kv < qt) stage(cur ^ 1, k0 + 64);

            const char* kb = (const char*)Kl + (cur << 13);
            const char* vb = (const char*)Vl + (cur << 13);

            // S^T = K Q^T over this wave's 32 k-cols (Q pre-scaled, log2 domain)
            f32x4 s[2];
            __builtin_amdgcn_s_setprio(1);
#pragma unroll
            for (int nt = 0; nt < 2; nt++) {
                f32x4 z = (f32x4){0.f, 0.f, 0.f, 0.f};
                z = __builtin_amdgcn_mfma_f32_16x16x32_bf16(*(const short8*)(kb + koff[nt][0]), qf0, z, 0, 0, 0);
                z = __builtin_amdgcn_mfma_f32_16x16x32_bf16(*(const short8*)(kb + koff[nt][1]), qf1, z, 0, 0, 0);
                s[nt] = z;
            }
            __builtin_amdgcn_s_setprio(0);

            // causal mask (diagonal tile only)
            if (kv == qt) {
#pragma unroll
                for (int nt = 0; nt < 2; nt++) {
                    int kbi = k0 + kh * 32 + nt * 16 + 4 * g;
#pragma unroll
                    for (int j = 0; j < 4; j++)
                        if (kbi + j > q) s[nt][j] = NEGINF;
                }
            }

            // tile max: max3-friendly tree + 2 shuffle rounds
            float t0 = fmaxf(fmaxf(s[0][0], s[0][1]), s[0][2]);
            float t1 = fmaxf(fmaxf(s[0][3], s[1][0]), s[1][1]);
            float t2 = fmaxf(s[1][2], s[1][3]);
            float mt = fmaxf(fmaxf(t0, t1), t2);
            mt = fmaxf(mt, __shfl_xor(mt, 16));
            mt = fmaxf(mt, __shfl_xor(mt, 32));

            // defer-max: rescale only when tile max exceeds running max by >8 (log2)
            if (mt > mrun + 8.f) {
                float corr = __builtin_exp2f(mrun - mt);
                mrun = mt;
                srun *= corr;
#pragma unroll
                for (int dt = 0; dt < 4; dt++)
#pragma unroll
                    for (int j = 0; j < 4; j++) o[dt][j] *= corr;
            }

#pragma unroll
            for (int nt = 0; nt < 2; nt++)
#pragma unroll
                for (int j = 0; j < 4; j++)
                    s[nt][j] = __builtin_exp2f(s[nt][j] - mrun);

            // P -> LDS packed via cvt_pk (2x ds_write_b64), fragment back
#pragma unroll
            for (int nt = 0; nt < 2; nt++) {
                uint2 pk;
                pk.x = cvtpk(s[nt][0], s[nt][1]);
                pk.y = cvtpk(s[nt][2], s[nt][3]);
                *(uint2*)&myPs[r][nt * 16 + 4 * g] = pk;
            }
            short8 pf = *(short8*)&myPs[r][8 * g];

            __builtin_amdgcn_s_setprio(1);
#pragma unroll
            for (int dt = 0; dt < 4; dt++)
                o[dt] = __builtin_amdgcn_mfma_f32_16x16x32_bf16(*(const short8*)(vb + voff[dt]), pf, o[dt], 0, 0, 0);
            // row-sum of P via ones-MFMA (replaces 8 fadd + 2 shuffles)
            f32x4 zs = (f32x4){0.f, 0.f, 0.f, 0.f};
            zs = __builtin_amdgcn_mfma_f32_16x16x32_bf16(onesf, pf, zs, 0, 0, 0);
            __builtin_amdgcn_s_setprio(0);
            srun += zs[0];
        }

        // -------- merge kh partials (flash combine, log2 domain) + epilogue --------
        __syncthreads();                         // all tile compute done; Kl reusable
        float* mb = ((float*)&Kl[0][0]) + ((rg * 64 + lane) * 18);
        if (kh) {
#pragma unroll
            for (int dt = 0; dt < 4; dt++) *(f32x4*)&mb[dt * 4] = o[dt];
            mb[16] = mrun;
            mb[17] = srun;
        }
        __syncthreads();
        if (!kh) {
            float m1 = mb[16], l1 = mb[17];
            float mm = fmaxf(mrun, m1);
            float c0 = __builtin_exp2f(mrun - mm);
            float c1 = __builtin_exp2f(m1 - mm);
            float inv = 1.f / (srun * c0 + l1 * c1);
            float s0 = c0 * inv, s1 = c1 * inv;
#pragma unroll
            for (int dt = 0; dt < 4; dt++) {
                f32x4 o1 = *(const f32x4*)&mb[dt * 4];
                uint2 pk;
                pk.x = cvtpk(o[dt][0] * s0 + o1[0] * s1, o[dt][1] * s0 + o1[1] * s1);
                pk.y = cvtpk(o[dt][2] * s0 + o1[2] * s1, o[dt][3] * s0 + o1[3] * s1);
                *(uint2*)&O[(((size_t)(b * T_SEQ + q)) * NH + h) * HD + dt * 16 + 4 * g] = pk;
            }
        }
    }
}

extern "C" void kernel_launch(void* const* d_in, const int* in_sizes, int n_in,
                              void* d_out, int out_size, void* d_ws, size_t ws_size,
                              hipStream_t stream) {
    const float* x     = (const float*)d_in[0];
    const float* W_qkv = (const float*)d_in[1];
    const float* b_qkv = (const float*)d_in[2];
    const float* W_out = (const float*)d_in[3];
    const float* b_out = (const float*)d_in[4];
    float* out = (float*)d_out;

    char* ws = (char*)d_ws;
    u16* xb    = (u16*)(ws);
    u16* wqkvt = (u16*)(ws + 8388608);
    u16* woutt = (u16*)(ws + 14680064);
    u16* Qp    = (u16*)(ws + 16777216);
    u16* Kp    = (u16*)(ws + 25165824);
    u16* VTp   = (u16*)(ws + 33554432);
    u16* attnb = (u16*)(ws);   // alias xb (dead after gemm_qkv)

    cast_bf16_kernel<<<4096, 256, 0, stream>>>(x, xb, 1048576);
    transpose_cast_kernel<<<dim3(96, 32), dim3(32, 8), 0, stream>>>(W_qkv, wqkvt, 1024, 3072);
    transpose_cast_kernel<<<dim3(32, 32), dim3(32, 8), 0, stream>>>(W_out, woutt, 1024, 1024);
    gemm_qkv_kernel<<<dim3(32, 24), 256, 0, stream>>>(xb, wqkvt, b_qkv, Qp, Kp, VTp);
    attn_kernel<<<512, 512, 0, stream>>>(Qp, Kp, VTp, attnb);
    gemm_out_kernel<<<dim3(32, 8), 256, 0, stream>>>(attnb, woutt, b_out, out);
}

// Round 8
// 126.349 us; speedup vs baseline: 2.7613x; 1.0314x over previous
//
#include <hip/hip_runtime.h>
#include <hip/hip_bf16.h>
#include <stdint.h>

typedef unsigned short u16;
typedef __attribute__((ext_vector_type(8))) short short8;
typedef __attribute__((ext_vector_type(4))) float f32x4;

#define T_SEQ 2048
#define EMB   1024
#define NH    16
#define HD    64

__device__ __forceinline__ u16 f2bf(float f) {
    union { float f; uint32_t u; } x; x.f = f;
    uint32_t u = x.u;
    uint32_t r = u + 0x7fffu + ((u >> 16) & 1u);   // RNE
    return (u16)(r >> 16);
}

// packed fp32x2 -> bf16x2 (RNE), single instruction; lo = first arg (verified R5)
__device__ __forceinline__ uint32_t cvtpk(float a, float b) {
    uint32_t r;
    asm("v_cvt_pk_bf16_f32 %0, %1, %2" : "=v"(r) : "v"(a), "v"(b));
    return r;
}

// async global -> LDS, 16 bytes per lane (wave-uniform LDS base + lane*16)
__device__ __forceinline__ void gld16(const void* g, void* l) {
    __builtin_amdgcn_global_load_lds(
        (const __attribute__((address_space(1))) void*)g,
        (__attribute__((address_space(3))) void*)l, 16, 0, 0);
}

// ---------------- cast fp32 -> bf16 (vectorized) ----------------
__global__ __launch_bounds__(256) void cast_bf16_kernel(const float* __restrict__ in,
                                                        u16* __restrict__ out, int n4) {
    int i = blockIdx.x * 256 + threadIdx.x;
    if (i < n4) {
        float4 v = ((const float4*)in)[i];
        ((uint2*)out)[i] = make_uint2(cvtpk(v.x, v.y), cvtpk(v.z, v.w));
    }
}

// ---------------- transpose + cast: Wt[n][k] = bf16(W[k][n]) ----------------
__global__ __launch_bounds__(256) void transpose_cast_kernel(const float* __restrict__ W,
                                                             u16* __restrict__ Wt,
                                                             int K, int N) {
    __shared__ float tile[32][33];
    int n0 = blockIdx.x * 32, k0 = blockIdx.y * 32;
    int tx = threadIdx.x, ty = threadIdx.y;   // 32 x 8
#pragma unroll
    for (int i = 0; i < 4; i++)
        tile[ty + i * 8][tx] = W[(k0 + ty + i * 8) * N + n0 + tx];
    __syncthreads();
#pragma unroll
    for (int i = 0; i < 4; i++)
        Wt[(size_t)(n0 + ty + i * 8) * K + k0 + tx] = f2bf(tile[tx][ty + i * 8]);
}

// ---------------- 128x128 tile GEMM core (K=1024, BK=32, 4 waves) ----------------
// Double-buffered (T3 minimal): barrier -> stage(next) -> compute(cur).
__device__ __forceinline__ void gemm_tile(const u16* __restrict__ A, const u16* __restrict__ Bt,
                                          int m0, int n0, f32x4 (&acc)[4][4],
                                          u16* As, u16* Bs, int tid) {
    const int lane = tid & 63;
    const int wid  = tid >> 6;
    const int wr = wid >> 1, wc = wid & 1;
    const int g = lane >> 4, r = lane & 15;
#pragma unroll
    for (int m = 0; m < 4; m++)
#pragma unroll
        for (int n = 0; n < 4; n++) acc[m][n] = (f32x4){0.f, 0.f, 0.f, 0.f};

    // staging geometry: thread covers 16B of row (tid/4) and (tid/4 + 64)
    const int srow = tid >> 2;
    const int skb  = (tid & 3) * 8;
    const u16* ag = A  + (size_t)(m0 + srow) * 1024 + skb;
    const u16* bg = Bt + (size_t)(n0 + srow) * 1024 + skb;
    char* asl = (char*)As + tid * 16;
    char* bsl = (char*)Bs + tid * 16;

    auto stage = [&](int buf, int kk) {
        gld16(ag + kk,             asl + buf * 8192);
        gld16(ag + kk + 64 * 1024, asl + buf * 8192 + 4096);
        gld16(bg + kk,             bsl + buf * 8192);
        gld16(bg + kk + 64 * 1024, bsl + buf * 8192 + 4096);
    };

    stage(0, 0);
    for (int it = 0; it < 32; ++it) {
        const int cur = it & 1;
        __syncthreads();                      // buf[cur] staged (barrier drains vmcnt)
        if (it < 31) stage(cur ^ 1, (it + 1) * 32);
        const u16* as = As + cur * 4096;
        const u16* bs = Bs + cur * 4096;
        short8 af[4], bf[4];
#pragma unroll
        for (int m = 0; m < 4; m++) af[m] = *(const short8*)&as[(wr * 64 + m * 16 + r) * 32 + g * 8];
#pragma unroll
        for (int n = 0; n < 4; n++) bf[n] = *(const short8*)&bs[(wc * 64 + n * 16 + r) * 32 + g * 8];
#pragma unroll
        for (int m = 0; m < 4; m++)
#pragma unroll
            for (int n = 0; n < 4; n++)
                acc[m][n] = __builtin_amdgcn_mfma_f32_16x16x32_bf16(af[m], bf[n], acc[m][n], 0, 0, 0);
    }
}

// ---------------- QKV GEMM: Q pre-scaled by 0.125*log2(e), K -> [B,H,T,D]; V -> VT [B,H,D,T] ----
__global__ __launch_bounds__(256) void gemm_qkv_kernel(const u16* __restrict__ A, const u16* __restrict__ Bt,
                                                       const float* __restrict__ bias,
                                                       u16* __restrict__ Qo, u16* __restrict__ Ko,
                                                       u16* __restrict__ VTo) {
    __shared__ __align__(16) u16 As[2][128 * 32];
    __shared__ __align__(16) u16 Bs[2][128 * 32];
    int tid = threadIdx.x;
    int m0 = blockIdx.x * 128, n0 = blockIdx.y * 128;
    f32x4 acc[4][4];
    gemm_tile(A, Bt, m0, n0, acc, &As[0][0], &Bs[0][0], tid);

    int lane = tid & 63, wid = tid >> 6;
    int wr = wid >> 1, wc = wid & 1, g = lane >> 4, r = lane & 15;
#pragma unroll
    for (int m = 0; m < 4; m++) {
#pragma unroll
        for (int n = 0; n < 4; n++) {
            int col = n0 + wc * 64 + n * 16 + r;     // [0,3072)
            float bv = bias[col];
            int which = col >> 10;
            int e = col & 1023;
            int h = e >> 6, d = e & 63;
            int row0 = m0 + wr * 64 + m * 16 + g * 4;   // token base, multiple of 4
            int b = row0 >> 11, t0 = row0 & 2047;
            if (which == 2) {
                uint2 pk;
                pk.x = cvtpk(acc[m][n][0] + bv, acc[m][n][1] + bv);
                pk.y = cvtpk(acc[m][n][2] + bv, acc[m][n][3] + bv);
                *(uint2*)&VTo[(((size_t)(b * NH + h)) * HD + d) * T_SEQ + t0] = pk;
            } else {
                u16* dst = which ? Ko : Qo;
                // Q: fold 1/sqrt(D) AND log2(e) so attn uses exp2 directly
                float sc = which ? 1.0f : 0.18033688011112042f;
#pragma unroll
                for (int j = 0; j < 4; j++)
                    dst[(((size_t)(b * NH + h)) * T_SEQ + t0 + j) * HD + d] = f2bf((acc[m][n][j] + bv) * sc);
            }
        }
    }
}

// ---------------- output GEMM: fp32 out = A @ Wout + b ----------------
__global__ __launch_bounds__(256) void gemm_out_kernel(const u16* __restrict__ A, const u16* __restrict__ Bt,
                                                       const float* __restrict__ bias,
                                                       float* __restrict__ out) {
    __shared__ __align__(16) u16 As[2][128 * 32];
    __shared__ __align__(16) u16 Bs[2][128 * 32];
    int tid = threadIdx.x;
    int m0 = blockIdx.x * 128, n0 = blockIdx.y * 128;
    f32x4 acc[4][4];
    gemm_tile(A, Bt, m0, n0, acc, &As[0][0], &Bs[0][0], tid);

    int lane = tid & 63, wid = tid >> 6;
    int wr = wid >> 1, wc = wid & 1, g = lane >> 4, r = lane & 15;
#pragma unroll
    for (int m = 0; m < 4; m++) {
#pragma unroll
        for (int n = 0; n < 4; n++) {
            int col = n0 + wc * 64 + n * 16 + r;
            float bv = bias[col];
#pragma unroll
            for (int j = 0; j < 4; j++) {
                int row = m0 + wr * 64 + m * 16 + g * 4 + j;
                out[(size_t)row * 1024 + col] = acc[m][n][j] + bv;
            }
        }
    }
}

// ---------------- causal flash attention ----------------
// grid: 1024 blocks 1D, heavy-first LPT: qt = 31 - bid/32, bh = bid & 31
// (bh & 7 == bid & 7 keeps each head-group pinned to one XCD's L2).
// Block = 512 threads = 8 waves: rg = wid&3 (16 q-rows), kh = wid>>2 (32 k-cols).
// K/V^T staged in LDS dbuf (swizzled global_load_lds); swapped S^T = mfma(K,Q).
// Row-sum via ones-MFMA; kh partials merged once at the end via LDS.
__global__ __launch_bounds__(512) void attn_kernel(const u16* __restrict__ Q, const u16* __restrict__ K,
                                                   const u16* __restrict__ VT, u16* __restrict__ O) {
    __shared__ __align__(16) char smem[43008];
    u16* Kl = (u16*)smem;                         // [2][64*64] swizzled K tiles
    u16* Vl = (u16*)(smem + 16384);               // [2][64*64] swizzled V^T tiles
    u16 (*Ps)[16][40] = (u16(*)[16][40])(smem + 32768);  // per-wave P, 80B rows

    const int tid = threadIdx.x;
    const int lane = tid & 63, wid = tid >> 6;
    const int g = lane >> 4, r = lane & 15;
    const int rg = wid & 3, kh = wid >> 2;
    const int bid = blockIdx.x;
    const int qt = 31 - (bid >> 5);
    const int bh = bid & 31;
    const int b = bh >> 4, h = bh & 15;
    const u16* Qb  = Q  + (size_t)bh * T_SEQ * HD;
    const u16* Kb  = K  + (size_t)bh * T_SEQ * HD;
    const u16* VTb = VT + (size_t)bh * HD * T_SEQ;
    u16 (*myPs)[40] = Ps[wid];
    const float NEGINF = -__builtin_inff();

    // hoisted lane-constant LDS read offsets (swizzled)
    int koff[2][2], voff[4];
#pragma unroll
    for (int nt = 0; nt < 2; nt++)
#pragma unroll
        for (int hh = 0; hh < 2; hh++)
            koff[nt][hh] = ((kh * 2 + nt) * 16 + r) * 128 + ((((hh * 4 + g) ^ (r & 7)) << 4));
#pragma unroll
    for (int dt = 0; dt < 4; dt++)
        voff[dt] = (dt * 16 + r) * 128 + ((((kh * 4 + g) ^ (r & 7)) << 4));

    // hoisted staging addresses (vary only by k0 / buf)
    const int srow = tid >> 3;
    const int sm = (tid & 7) ^ (srow & 7);
    const u16* kgp = Kb + srow * HD + sm * 8;
    const u16* vgp = VTb + (size_t)srow * T_SEQ + sm * 8;
    char* kld = (char*)Kl + tid * 16;
    char* vld = (char*)Vl + tid * 16;
    auto stage = [&](int buf, int k0) {
        gld16(kgp + (size_t)k0 * HD, kld + (buf << 13));
        gld16(vgp + k0, vld + (buf << 13));
    };

    short8 onesf;
#pragma unroll
    for (int i = 0; i < 8; i++) onesf[i] = (short)0x3F80;   // bf16 1.0

    const int q0 = qt * 64;
    const int q  = q0 + rg * 16 + r;             // this lane's q row (fixed)

    stage(0, 0);

    // Q fragments (B-operand: col = lane%16 -> q, 8 contiguous d per lane)
    short8 qf0 = *(const short8*)&Qb[(size_t)q * HD + 8 * g];
    short8 qf1 = *(const short8*)&Qb[(size_t)q * HD + 32 + 8 * g];

    float mrun = -1e30f, srun = 0.f;
    f32x4 o[4];
#pragma unroll
    for (int dt = 0; dt < 4; dt++) o[dt] = (f32x4){0.f, 0.f, 0.f, 0.f};

    for (int kv = 0; kv <= qt; kv++) {
        const int cur = kv & 1;
        const int k0 = kv * 64;
        __syncthreads();                         // buf[cur] staged (vmcnt drained)
        if (kv < qt) stage(cur ^ 1, k0 + 64);

        const char* kb = (const char*)Kl + (cur << 13);
        const char* vb = (const char*)Vl + (cur << 13);

        // S^T = K Q^T over this wave's 32 k-cols (Q pre-scaled, log2 domain)
        f32x4 s[2];
        __builtin_amdgcn_s_setprio(1);
#pragma unroll
        for (int nt = 0; nt < 2; nt++) {
            f32x4 z = (f32x4){0.f, 0.f, 0.f, 0.f};
            z = __builtin_amdgcn_mfma_f32_16x16x32_bf16(*(const short8*)(kb + koff[nt][0]), qf0, z, 0, 0, 0);
            z = __builtin_amdgcn_mfma_f32_16x16x32_bf16(*(const short8*)(kb + koff[nt][1]), qf1, z, 0, 0, 0);
            s[nt] = z;
        }
        __builtin_amdgcn_s_setprio(0);

        // causal mask (diagonal tile only)
        if (kv == qt) {
#pragma unroll
            for (int nt = 0; nt < 2; nt++) {
                int kbi = k0 + kh * 32 + nt * 16 + 4 * g;
#pragma unroll
                for (int j = 0; j < 4; j++)
                    if (kbi + j > q) s[nt][j] = NEGINF;
            }
        }

        // tile max: max3-friendly tree + 2 shuffle rounds
        float t0 = fmaxf(fmaxf(s[0][0], s[0][1]), s[0][2]);
        float t1 = fmaxf(fmaxf(s[0][3], s[1][0]), s[1][1]);
        float t2 = fmaxf(s[1][2], s[1][3]);
        float mt = fmaxf(fmaxf(t0, t1), t2);
        mt = fmaxf(mt, __shfl_xor(mt, 16));
        mt = fmaxf(mt, __shfl_xor(mt, 32));

        // defer-max: rescale only when tile max exceeds running max by >8 (log2)
        if (mt > mrun + 8.f) {
            float corr = __builtin_exp2f(mrun - mt);
            mrun = mt;
            srun *= corr;
#pragma unroll
            for (int dt = 0; dt < 4; dt++)
#pragma unroll
                for (int j = 0; j < 4; j++) o[dt][j] *= corr;
        }

#pragma unroll
        for (int nt = 0; nt < 2; nt++)
#pragma unroll
            for (int j = 0; j < 4; j++)
                s[nt][j] = __builtin_exp2f(s[nt][j] - mrun);

        // P -> LDS packed via cvt_pk (2x ds_write_b64), fragment back
#pragma unroll
        for (int nt = 0; nt < 2; nt++) {
            uint2 pk;
            pk.x = cvtpk(s[nt][0], s[nt][1]);
            pk.y = cvtpk(s[nt][2], s[nt][3]);
            *(uint2*)&myPs[r][nt * 16 + 4 * g] = pk;
        }
        short8 pf = *(short8*)&myPs[r][8 * g];

        __builtin_amdgcn_s_setprio(1);
#pragma unroll
        for (int dt = 0; dt < 4; dt++)
            o[dt] = __builtin_amdgcn_mfma_f32_16x16x32_bf16(*(const short8*)(vb + voff[dt]), pf, o[dt], 0, 0, 0);
        // row-sum of P via ones-MFMA (replaces 8 fadd + 2 shuffles)
        f32x4 zs = (f32x4){0.f, 0.f, 0.f, 0.f};
        zs = __builtin_amdgcn_mfma_f32_16x16x32_bf16(onesf, pf, zs, 0, 0, 0);
        __builtin_amdgcn_s_setprio(0);
        srun += zs[0];
    }

    // -------- merge kh partials (flash combine, log2 domain) + epilogue --------
    __syncthreads();                             // all tile compute done; smem reusable
    float* mb = ((float*)smem) + ((rg * 64 + lane) * 18);
    if (kh) {
#pragma unroll
        for (int dt = 0; dt < 4; dt++) *(f32x4*)&mb[dt * 4] = o[dt];
        mb[16] = mrun;
        mb[17] = srun;
    }
    __syncthreads();
    if (!kh) {
        float m1 = mb[16], l1 = mb[17];
        float mm = fmaxf(mrun, m1);
        float c0 = __builtin_exp2f(mrun - mm);
        float c1 = __builtin_exp2f(m1 - mm);
        float inv = 1.f / (srun * c0 + l1 * c1);
        float s0 = c0 * inv, s1 = c1 * inv;
#pragma unroll
        for (int dt = 0; dt < 4; dt++) {
            f32x4 o1 = *(const f32x4*)&mb[dt * 4];
            uint2 pk;
            pk.x = cvtpk(o[dt][0] * s0 + o1[0] * s1, o[dt][1] * s0 + o1[1] * s1);
            pk.y = cvtpk(o[dt][2] * s0 + o1[2] * s1, o[dt][3] * s0 + o1[3] * s1);
            *(uint2*)&O[(((size_t)(b * T_SEQ + q)) * NH + h) * HD + dt * 16 + 4 * g] = pk;
        }
    }
}

extern "C" void kernel_launch(void* const* d_in, const int* in_sizes, int n_in,
                              void* d_out, int out_size, void* d_ws, size_t ws_size,
                              hipStream_t stream) {
    const float* x     = (const float*)d_in[0];
    const float* W_qkv = (const float*)d_in[1];
    const float* b_qkv = (const float*)d_in[2];
    const float* W_out = (const float*)d_in[3];
    const float* b_out = (const float*)d_in[4];
    float* out = (float*)d_out;

    char* ws = (char*)d_ws;
    u16* xb    = (u16*)(ws);
    u16* wqkvt = (u16*)(ws + 8388608);
    u16* woutt = (u16*)(ws + 14680064);
    u16* Qp    = (u16*)(ws + 16777216);
    u16* Kp    = (u16*)(ws + 25165824);
    u16* VTp   = (u16*)(ws + 33554432);
    u16* attnb = (u16*)(ws);   // alias xb (dead after gemm_qkv)

    cast_bf16_kernel<<<4096, 256, 0, stream>>>(x, xb, 1048576);
    transpose_cast_kernel<<<dim3(96, 32), dim3(32, 8), 0, stream>>>(W_qkv, wqkvt, 1024, 3072);
    transpose_cast_kernel<<<dim3(32, 32), dim3(32, 8), 0, stream>>>(W_out, woutt, 1024, 1024);
    gemm_qkv_kernel<<<dim3(32, 24), 256, 0, stream>>>(xb, wqkvt, b_qkv, Qp, Kp, VTp);
    attn_kernel<<<1024, 512, 0, stream>>>(Qp, Kp, VTp, attnb);
    gemm_out_kernel<<<dim3(32, 8), 256, 0, stream>>>(attnb, woutt, b_out, out);
}

// Round 11
// 118.743 us; speedup vs baseline: 2.9382x; 1.0641x over previous
//
#include <hip/hip_runtime.h>
#include <hip/hip_bf16.h>
#include <stdint.h>

typedef unsigned short u16;
typedef __attribute__((ext_vector_type(8))) short short8;
typedef __attribute__((ext_vector_type(4))) float f32x4;

#define T_SEQ 2048
#define EMB   1024
#define NH    16
#define HD    64

__device__ __forceinline__ u16 f2bf(float f) {
    union { float f; uint32_t u; } x; x.f = f;
    uint32_t u = x.u;
    uint32_t r = u + 0x7fffu + ((u >> 16) & 1u);   // RNE
    return (u16)(r >> 16);
}

// packed fp32x2 -> bf16x2 (RNE), single instruction; lo = first arg (verified R5-R8)
__device__ __forceinline__ uint32_t cvtpk(float a, float b) {
    uint32_t r;
    asm("v_cvt_pk_bf16_f32 %0, %1, %2" : "=v"(r) : "v"(a), "v"(b));
    return r;
}

// async global -> LDS, 16 bytes per lane (wave-uniform LDS base + lane*16)
__device__ __forceinline__ void gld16(const void* g, void* l) {
    __builtin_amdgcn_global_load_lds(
        (const __attribute__((address_space(1))) void*)g,
        (__attribute__((address_space(3))) void*)l, 16, 0, 0);
}

// ---------------- prep: cast x -> bf16, transpose+cast both weights (one launch) ----
__global__ __launch_bounds__(256) void prep_kernel(const float* __restrict__ x, u16* __restrict__ xb,
                                                   const float* __restrict__ Wq, u16* __restrict__ Wqt,
                                                   const float* __restrict__ Wo, u16* __restrict__ Wot) {
    __shared__ float tile[32][33];
    const int bid = blockIdx.x;
    if (bid < 4096) {                       // cast branch: 4096 blocks x 256 x float4
        int i = bid * 256 + threadIdx.x;
        float4 v = ((const float4*)x)[i];
        ((uint2*)xb)[i] = make_uint2(cvtpk(v.x, v.y), cvtpk(v.z, v.w));
        return;
    }
    int t = bid - 4096;
    const float* W; u16* Wt; int N;
    if (t < 3072) { W = Wq; Wt = Wqt; N = 3072; }
    else          { W = Wo; Wt = Wot; N = 1024; t -= 3072; }
    const int ntiles = N >> 5;
    const int n0 = (t % ntiles) * 32, k0 = (t / ntiles) * 32;
    const int tx = threadIdx.x & 31, ty = threadIdx.x >> 5;   // 32 x 8
#pragma unroll
    for (int i = 0; i < 4; i++)
        tile[ty + i * 8][tx] = W[(size_t)(k0 + ty + i * 8) * N + n0 + tx];
    __syncthreads();
#pragma unroll
    for (int i = 0; i < 4; i++)
        Wt[(size_t)(n0 + ty + i * 8) * 1024 + k0 + tx] = f2bf(tile[tx][ty + i * 8]);
}

// ---------------- 128x128 tile GEMM core (K=1024, BK=32, 4 waves) ----------------
// Double-buffered (T3 minimal): barrier -> stage(next) -> compute(cur).
__device__ __forceinline__ void gemm_tile(const u16* __restrict__ A, const u16* __restrict__ Bt,
                                          int m0, int n0, f32x4 (&acc)[4][4],
                                          u16* As, u16* Bs, int tid) {
    const int lane = tid & 63;
    const int wid  = tid >> 6;
    const int wr = wid >> 1, wc = wid & 1;
    const int g = lane >> 4, r = lane & 15;
#pragma unroll
    for (int m = 0; m < 4; m++)
#pragma unroll
        for (int n = 0; n < 4; n++) acc[m][n] = (f32x4){0.f, 0.f, 0.f, 0.f};

    const int srow = tid >> 2;
    const int skb  = (tid & 3) * 8;
    const u16* ag = A  + (size_t)(m0 + srow) * 1024 + skb;
    const u16* bg = Bt + (size_t)(n0 + srow) * 1024 + skb;
    char* asl = (char*)As + tid * 16;
    char* bsl = (char*)Bs + tid * 16;

    auto stage = [&](int buf, int kk) {
        gld16(ag + kk,             asl + buf * 8192);
        gld16(ag + kk + 64 * 1024, asl + buf * 8192 + 4096);
        gld16(bg + kk,             bsl + buf * 8192);
        gld16(bg + kk + 64 * 1024, bsl + buf * 8192 + 4096);
    };

    stage(0, 0);
    for (int it = 0; it < 32; ++it) {
        const int cur = it & 1;
        __syncthreads();                      // buf[cur] staged (barrier drains vmcnt)
        if (it < 31) stage(cur ^ 1, (it + 1) * 32);
        const u16* as = As + cur * 4096;
        const u16* bs = Bs + cur * 4096;
        short8 af[4], bf[4];
#pragma unroll
        for (int m = 0; m < 4; m++) af[m] = *(const short8*)&as[(wr * 64 + m * 16 + r) * 32 + g * 8];
#pragma unroll
        for (int n = 0; n < 4; n++) bf[n] = *(const short8*)&bs[(wc * 64 + n * 16 + r) * 32 + g * 8];
#pragma unroll
        for (int m = 0; m < 4; m++)
#pragma unroll
            for (int n = 0; n < 4; n++)
                acc[m][n] = __builtin_amdgcn_mfma_f32_16x16x32_bf16(af[m], bf[n], acc[m][n], 0, 0, 0);
    }
}

// ---------------- QKV GEMM: Q pre-scaled by 0.125*log2(e), K -> [B,H,T,D]; V -> VT [B,H,D,T] ----
__global__ __launch_bounds__(256) void gemm_qkv_kernel(const u16* __restrict__ A, const u16* __restrict__ Bt,
                                                       const float* __restrict__ bias,
                                                       u16* __restrict__ Qo, u16* __restrict__ Ko,
                                                       u16* __restrict__ VTo) {
    __shared__ __align__(16) u16 As[2][128 * 32];
    __shared__ __align__(16) u16 Bs[2][128 * 32];
    int tid = threadIdx.x;
    int m0 = blockIdx.x * 128, n0 = blockIdx.y * 128;
    f32x4 acc[4][4];
    gemm_tile(A, Bt, m0, n0, acc, &As[0][0], &Bs[0][0], tid);

    int lane = tid & 63, wid = tid >> 6;
    int wr = wid >> 1, wc = wid & 1, g = lane >> 4, r = lane & 15;
#pragma unroll
    for (int m = 0; m < 4; m++) {
#pragma unroll
        for (int n = 0; n < 4; n++) {
            int col = n0 + wc * 64 + n * 16 + r;     // [0,3072)
            float bv = bias[col];
            int which = col >> 10;
            int e = col & 1023;
            int h = e >> 6, d = e & 63;
            int row0 = m0 + wr * 64 + m * 16 + g * 4;   // token base, multiple of 4
            int b = row0 >> 11, t0 = row0 & 2047;
            if (which == 2) {
                uint2 pk;
                pk.x = cvtpk(acc[m][n][0] + bv, acc[m][n][1] + bv);
                pk.y = cvtpk(acc[m][n][2] + bv, acc[m][n][3] + bv);
                *(uint2*)&VTo[(((size_t)(b * NH + h)) * HD + d) * T_SEQ + t0] = pk;
            } else {
                u16* dst = which ? Ko : Qo;
                // Q: fold 1/sqrt(D) AND log2(e) so attn uses exp2 directly
                float sc = which ? 1.0f : 0.18033688011112042f;
#pragma unroll
                for (int j = 0; j < 4; j++)
                    dst[(((size_t)(b * NH + h)) * T_SEQ + t0 + j) * HD + d] = f2bf((acc[m][n][j] + bv) * sc);
            }
        }
    }
}

// ---------------- output GEMM: 64x128 tile (512 blocks = 2/CU), fp32 out ----------------
__global__ __launch_bounds__(256) void gemm_out_kernel(const u16* __restrict__ A, const u16* __restrict__ Bt,
                                                       const float* __restrict__ bias,
                                                       float* __restrict__ out) {
    __shared__ __align__(16) u16 As[2][64 * 32];
    __shared__ __align__(16) u16 Bs[2][128 * 32];
    const int tid = threadIdx.x;
    const int m0 = blockIdx.x * 64, n0 = blockIdx.y * 128;
    const int lane = tid & 63, wid = tid >> 6;      // 4 waves, 1 x 4 (wc = wid)
    const int g = lane >> 4, r = lane & 15;

    f32x4 acc[4][2];
#pragma unroll
    for (int m = 0; m < 4; m++)
#pragma unroll
        for (int n = 0; n < 2; n++) acc[m][n] = (f32x4){0.f, 0.f, 0.f, 0.f};

    const int srow = tid >> 2;
    const int skb  = (tid & 3) * 8;
    const u16* ag = A  + (size_t)(m0 + srow) * 1024 + skb;
    const u16* bg = Bt + (size_t)(n0 + srow) * 1024 + skb;
    char* asl = (char*)As + tid * 16;
    char* bsl = (char*)Bs + tid * 16;

    auto stage = [&](int buf, int kk) {
        gld16(ag + kk,             asl + buf * 4096);
        gld16(bg + kk,             bsl + buf * 8192);
        gld16(bg + kk + 64 * 1024, bsl + buf * 8192 + 4096);
    };

    stage(0, 0);
    for (int it = 0; it < 32; ++it) {
        const int cur = it & 1;
        __syncthreads();
        if (it < 31) stage(cur ^ 1, (it + 1) * 32);
        const u16* as = &As[cur][0];
        const u16* bs = &Bs[cur][0];
        short8 af[4], bf[2];
#pragma unroll
        for (int m = 0; m < 4; m++) af[m] = *(const short8*)&as[(m * 16 + r) * 32 + g * 8];
#pragma unroll
        for (int n = 0; n < 2; n++) bf[n] = *(const short8*)&bs[(wid * 32 + n * 16 + r) * 32 + g * 8];
#pragma unroll
        for (int m = 0; m < 4; m++)
#pragma unroll
            for (int n = 0; n < 2; n++)
                acc[m][n] = __builtin_amdgcn_mfma_f32_16x16x32_bf16(af[m], bf[n], acc[m][n], 0, 0, 0);
    }

#pragma unroll
    for (int m = 0; m < 4; m++) {
#pragma unroll
        for (int n = 0; n < 2; n++) {
            int col = n0 + wid * 32 + n * 16 + r;
            float bv = bias[col];
#pragma unroll
            for (int j = 0; j < 4; j++) {
                int row = m0 + m * 16 + g * 4 + j;
                out[(size_t)row * 1024 + col] = acc[m][n][j] + bv;
            }
        }
    }
}

// ---------------- causal flash attention (R7-verified structure) ----------------
// grid: 1024 blocks 1D, heavy-first LPT: qt = 31 - bid/32, bh = bid & 31.
// Block = 512 threads = 8 waves: rg = wid&3 (16 q-rows), kh = wid>>2 (32 k-cols).
// K/V^T staged in LDS dbuf (swizzled global_load_lds); swapped S^T = mfma(K,Q).
// P transposed via per-wave LDS (verified); quad reduce via __shfl_xor (verified).
// Row-sum via ones-MFMA; kh partials merged once at the end via LDS.
__global__ __launch_bounds__(512) void attn_kernel(const u16* __restrict__ Q, const u16* __restrict__ K,
                                                   const u16* __restrict__ VT, u16* __restrict__ O) {
    __shared__ __align__(16) u16 Kl[2][64 * 64];    // [buf][k-row][64d], swizzled
    __shared__ __align__(16) u16 Vl[2][64 * 64];    // [buf][d][64k], swizzled
    __shared__ __align__(16) u16 Ps[8][16][40];     // per-wave P (q-major, 32k), 80B rows

    const int tid = threadIdx.x;
    const int lane = tid & 63, wid = tid >> 6;
    const int g = lane >> 4, r = lane & 15;
    const int rg = wid & 3, kh = wid >> 2;
    const int bid = blockIdx.x;
    const int qt = 31 - (bid >> 5);
    const int bh = bid & 31;
    const int b = bh >> 4, h = bh & 15;
    const u16* Qb  = Q  + (size_t)bh * T_SEQ * HD;
    const u16* Kb  = K  + (size_t)bh * T_SEQ * HD;
    const u16* VTb = VT + (size_t)bh * HD * T_SEQ;
    u16 (*myPs)[40] = Ps[wid];
    const float NEGINF = -__builtin_inff();

    // hoisted lane-constant LDS read offsets (swizzled)
    int koff[2][2], voff[4];
#pragma unroll
    for (int nt = 0; nt < 2; nt++)
#pragma unroll
        for (int hh = 0; hh < 2; hh++)
            koff[nt][hh] = ((kh * 2 + nt) * 16 + r) * 128 + ((((hh * 4 + g) ^ (r & 7)) << 4));
#pragma unroll
    for (int dt = 0; dt < 4; dt++)
        voff[dt] = (dt * 16 + r) * 128 + ((((kh * 4 + g) ^ (r & 7)) << 4));

    // hoisted staging addresses (vary only by k0 / buf)
    const int srow = tid >> 3;
    const int sm = (tid & 7) ^ (srow & 7);
    const u16* kgp = Kb + srow * HD + sm * 8;
    const u16* vgp = VTb + (size_t)srow * T_SEQ + sm * 8;
    char* kld = (char*)Kl + tid * 16;
    char* vld = (char*)Vl + tid * 16;
    auto stage = [&](int buf, int k0) {
        gld16(kgp + (size_t)k0 * HD, kld + (buf << 13));
        gld16(vgp + k0, vld + (buf << 13));
    };

    short8 onesf;
#pragma unroll
    for (int i = 0; i < 8; i++) onesf[i] = (short)0x3F80;   // bf16 1.0

    const int q0 = qt * 64;
    const int q  = q0 + rg * 16 + r;             // this lane's q row (fixed)

    stage(0, 0);

    // Q fragments (B-operand: col = lane%16 -> q, 8 contiguous d per lane)
    short8 qf0 = *(const short8*)&Qb[(size_t)q * HD + 8 * g];
    short8 qf1 = *(const short8*)&Qb[(size_t)q * HD + 32 + 8 * g];

    float mrun = -1e30f, srun = 0.f;
    f32x4 o[4];
#pragma unroll
    for (int dt = 0; dt < 4; dt++) o[dt] = (f32x4){0.f, 0.f, 0.f, 0.f};

    for (int kv = 0; kv <= qt; kv++) {
        const int cur = kv & 1;
        const int k0 = kv * 64;
        __syncthreads();                         // buf[cur] staged (vmcnt drained)
        if (kv < qt) stage(cur ^ 1, k0 + 64);

        const char* kb = (const char*)Kl + (cur << 13);
        const char* vb = (const char*)Vl + (cur << 13);

        // S^T = K Q^T over this wave's 32 k-cols (Q pre-scaled, log2 domain)
        f32x4 s[2];
        __builtin_amdgcn_s_setprio(1);
#pragma unroll
        for (int nt = 0; nt < 2; nt++) {
            f32x4 z = (f32x4){0.f, 0.f, 0.f, 0.f};
            z = __builtin_amdgcn_mfma_f32_16x16x32_bf16(*(const short8*)(kb + koff[nt][0]), qf0, z, 0, 0, 0);
            z = __builtin_amdgcn_mfma_f32_16x16x32_bf16(*(const short8*)(kb + koff[nt][1]), qf1, z, 0, 0, 0);
            s[nt] = z;
        }
        __builtin_amdgcn_s_setprio(0);

        // causal mask (diagonal tile only)
        if (kv == qt) {
#pragma unroll
            for (int nt = 0; nt < 2; nt++) {
                int kbi = k0 + kh * 32 + nt * 16 + 4 * g;
#pragma unroll
                for (int j = 0; j < 4; j++)
                    if (kbi + j > q) s[nt][j] = NEGINF;
            }
        }

        // tile max: max3-friendly tree + 2 shuffle rounds (verified)
        float t0 = fmaxf(fmaxf(s[0][0], s[0][1]), s[0][2]);
        float t1 = fmaxf(fmaxf(s[0][3], s[1][0]), s[1][1]);
        float t2 = fmaxf(s[1][2], s[1][3]);
        float mt = fmaxf(fmaxf(t0, t1), t2);
        mt = fmaxf(mt, __shfl_xor(mt, 16));
        mt = fmaxf(mt, __shfl_xor(mt, 32));

        // defer-max: rescale only when tile max exceeds running max by >8 (log2)
        if (mt > mrun + 8.f) {
            float corr = __builtin_exp2f(mrun - mt);
            mrun = mt;
            srun *= corr;
#pragma unroll
            for (int dt = 0; dt < 4; dt++)
#pragma unroll
                for (int j = 0; j < 4; j++) o[dt][j] *= corr;
        }

#pragma unroll
        for (int nt = 0; nt < 2; nt++)
#pragma unroll
            for (int j = 0; j < 4; j++)
                s[nt][j] = __builtin_exp2f(s[nt][j] - mrun);

        // P -> LDS packed via cvt_pk (2x ds_write_b64), fragment back (verified)
#pragma unroll
        for (int nt = 0; nt < 2; nt++) {
            uint2 pk;
            pk.x = cvtpk(s[nt][0], s[nt][1]);
            pk.y = cvtpk(s[nt][2], s[nt][3]);
            *(uint2*)&myPs[r][nt * 16 + 4 * g] = pk;
        }
        short8 pf = *(short8*)&myPs[r][8 * g];

        __builtin_amdgcn_s_setprio(1);
#pragma unroll
        for (int dt = 0; dt < 4; dt++)
            o[dt] = __builtin_amdgcn_mfma_f32_16x16x32_bf16(*(const short8*)(vb + voff[dt]), pf, o[dt], 0, 0, 0);
        // row-sum of P via ones-MFMA
        f32x4 zs = (f32x4){0.f, 0.f, 0.f, 0.f};
        zs = __builtin_amdgcn_mfma_f32_16x16x32_bf16(onesf, pf, zs, 0, 0, 0);
        __builtin_amdgcn_s_setprio(0);
        srun += zs[0];
    }

    // -------- merge kh partials (flash combine, log2 domain) + epilogue --------
    __syncthreads();                             // all tile compute done; smem reusable
    float* mb = ((float*)&Kl[0][0]) + ((rg * 64 + lane) * 18);
    if (kh) {
#pragma unroll
        for (int dt = 0; dt < 4; dt++) *(f32x4*)&mb[dt * 4] = o[dt];
        mb[16] = mrun;
        mb[17] = srun;
    }
    __syncthreads();
    if (!kh) {
        float m1 = mb[16], l1 = mb[17];
        float mm = fmaxf(mrun, m1);
        float c0 = __builtin_exp2f(mrun - mm);
        float c1 = __builtin_exp2f(m1 - mm);
        float inv = 1.f / (srun * c0 + l1 * c1);
        float s0 = c0 * inv, s1 = c1 * inv;
#pragma unroll
        for (int dt = 0; dt < 4; dt++) {
            f32x4 o1 = *(const f32x4*)&mb[dt * 4];
            uint2 pk;
            pk.x = cvtpk(o[dt][0] * s0 + o1[0] * s1, o[dt][1] * s0 + o1[1] * s1);
            pk.y = cvtpk(o[dt][2] * s0 + o1[2] * s1, o[dt][3] * s0 + o1[3] * s1);
            *(uint2*)&O[(((size_t)(b * T_SEQ + q)) * NH + h) * HD + dt * 16 + 4 * g] = pk;
        }
    }
}

extern "C" void kernel_launch(void* const* d_in, const int* in_sizes, int n_in,
                              void* d_out, int out_size, void* d_ws, size_t ws_size,
                              hipStream_t stream) {
    const float* x     = (const float*)d_in[0];
    const float* W_qkv = (const float*)d_in[1];
    const float* b_qkv = (const float*)d_in[2];
    const float* W_out = (const float*)d_in[3];
    const float* b_out = (const float*)d_in[4];
    float* out = (float*)d_out;

    char* ws = (char*)d_ws;
    u16* xb    = (u16*)(ws);
    u16* wqkvt = (u16*)(ws + 8388608);
    u16* woutt = (u16*)(ws + 14680064);
    u16* Qp    = (u16*)(ws + 16777216);
    u16* Kp    = (u16*)(ws + 25165824);
    u16* VTp   = (u16*)(ws + 33554432);
    u16* attnb = (u16*)(ws);   // alias xb (dead after gemm_qkv)

    prep_kernel<<<8192, 256, 0, stream>>>(x, xb, W_qkv, wqkvt, W_out, woutt);
    gemm_qkv_kernel<<<dim3(32, 24), 256, 0, stream>>>(xb, wqkvt, b_qkv, Qp, Kp, VTp);
    attn_kernel<<<1024, 512, 0, stream>>>(Qp, Kp, VTp, attnb);
    gemm_out_kernel<<<dim3(64, 8), 256, 0, stream>>>(attnb, woutt, b_out, out);
}